// Round 4
// baseline (13436.909 us; speedup 1.0000x reference)
//
#include <hip/hip_runtime.h>
#include <math.h>

#define N_NODES 30000
#define N_EDGES 480000
#define N_GRAPHS 16
#define HID 128
#define HEADS 8
#define HEAD_DIM 16
#define NODE_IN 64
#define EDGE_IN 32
#define COND 8
#define NODE_OUT 64
#define NLAYERS 4
#define EF (N_EDGES + N_NODES) /* 510000 */
#define LN_EPS 1e-5f

__device__ __forceinline__ float gelu_f(float x) {
    return 0.5f * x * (1.0f + erff(x * 0.70710678118654752440f));
}

__device__ __forceinline__ float dot4(float4 a, float4 b) {
    return a.x * b.x + a.y * b.y + a.z * b.z + a.w * b.w;
}

__device__ __forceinline__ void atomicMaxF(float* addr, float val) {
    if (val >= 0.0f) {
        atomicMax((int*)addr, __float_as_int(val));
    } else {
        atomicMin((unsigned int*)addr, __float_as_uint(val));
    }
}

// wave(64)-wide sum; all lanes end with the sum
__device__ __forceinline__ float wave_sum(float s) {
    s += __shfl_xor(s, 1);
    s += __shfl_xor(s, 2);
    s += __shfl_xor(s, 4);
    s += __shfl_xor(s, 8);
    s += __shfl_xor(s, 16);
    s += __shfl_xor(s, 32);
    return s;
}

// ---------- generic zero ----------
__global__ void zero_kernel(float* __restrict__ p, long n) {
    long i = (long)blockIdx.x * blockDim.x + threadIdx.x;
    long stride = (long)gridDim.x * blockDim.x;
    for (; i < n; i += stride) p[i] = 0.0f;
}

// ---------- transposes ----------
// in: [K,N] row-major -> out: [N,K] row-major
__global__ void transpose_kernel(const float* __restrict__ in, float* __restrict__ out,
                                 int K, int N) {
    int idx = blockIdx.x * blockDim.x + threadIdx.x;
    if (idx >= K * N) return;
    int k = idx / N, j = idx - k * N;
    out[j * K + k] = in[idx];
}

// 12 matrices of 128x128: cWl[0..3], cWr[0..3], cWe[0..3]
__global__ void batched_transpose12_kernel(const float* __restrict__ cWl,
                                           const float* __restrict__ cWr,
                                           const float* __restrict__ cWe,
                                           float* __restrict__ out) {
    int idx = blockIdx.x * blockDim.x + threadIdx.x;
    if (idx >= 12 * 16384) return;
    int m = idx >> 14;
    int r = idx & 16383;
    int k = r >> 7, j = r & 127;
    const float* base = (m < 4) ? (cWl + (size_t)m * 16384)
                      : (m < 8) ? (cWr + (size_t)(m - 4) * 16384)
                                : (cWe + (size_t)(m - 8) * 16384);
    out[(size_t)m * 16384 + j * 128 + k] = base[r];
}

// ---------- time MLP: t[16] -> t_emb[16,128] ----------
__global__ __launch_bounds__(128, 4) void time_mlp_kernel(
    const float* __restrict__ t,
    const float* __restrict__ tW1, const float* __restrict__ tb1,
    const float* __restrict__ tW2, const float* __restrict__ tb2,
    float* __restrict__ t_emb) {
    __shared__ float hsh[HID];
    int b = blockIdx.x, j = threadIdx.x;
    float tv = t[b];
    hsh[j] = gelu_f(tv * tW1[j] + tb1[j]);
    __syncthreads();
    float acc = tb2[j];
    for (int k = 0; k < HID; ++k) acc += hsh[k] * tW2[k * HID + j];
    t_emb[b * HID + j] = acc;
}

// ---------- concat x(64) + conditions[batch](8) -> xc[N,72] ----------
__global__ void concat_kernel(const float* __restrict__ x, const float* __restrict__ cond,
                              const int* __restrict__ batch, float* __restrict__ xc) {
    int idx = blockIdx.x * blockDim.x + threadIdx.x;
    if (idx >= N_NODES * 72) return;
    int n = idx / 72, c = idx % 72;
    xc[idx] = (c < NODE_IN) ? x[n * NODE_IN + c] : cond[batch[n] * COND + (c - NODE_IN)];
}

// ---------- generic GEMM (used only for the K=72 encoder) ----------
template <int NCOL, int R>
__global__ __launch_bounds__(128, 4) void gemm_kernel(
    const float* __restrict__ A, const float* __restrict__ B,
    const float* __restrict__ bias, float* __restrict__ C,
    int M, int K) {
    __shared__ float sh[R * HID];
    int j = threadIdx.x;
    int row0 = blockIdx.x * R;
    int total = R * K;
    for (int i = j; i < total; i += NCOL) {
        int r = i / K, k = i - r * K;
        int row = row0 + r;
        sh[r * K + k] = (row < M) ? A[(long)row * K + k] : 0.0f;
    }
    __syncthreads();
    float acc[R];
    float bv = bias ? bias[j] : 0.0f;
#pragma unroll
    for (int r = 0; r < R; ++r) acc[r] = bv;
    for (int k = 0; k < K; ++k) {
        float w = B[k * NCOL + j];
#pragma unroll
        for (int r = 0; r < R; ++r) acc[r] += sh[r * K + k] * w;
    }
#pragma unroll
    for (int r = 0; r < R; ++r) {
        int row = row0 + r;
        if (row < M) C[(long)row * NCOL + j] = acc[r];
    }
}

// ---------- GEMM with transposed B, K=128: C[M,NCOL] = A[M,128] @ BT^T + bias ----------
template <int NCOL, int R>
__global__ __launch_bounds__(128, 4) void gemm_t_kernel(
    const float* __restrict__ A, const float* __restrict__ BT,
    const float* __restrict__ bias, float* __restrict__ C, int M) {
    __shared__ __align__(16) float sh[R * HID];
    int j = threadIdx.x;
    int row0 = blockIdx.x * R;
    // stage A tile with float4
    const float4* A4 = (const float4*)A;
    float4* sh4 = (float4*)sh;
    for (int i = j; i < R * 32; i += NCOL) {
        int r = i >> 5, kq = i & 31;
        int row = row0 + r;
        sh4[i] = (row < M) ? A4[(long)row * 32 + kq] : make_float4(0, 0, 0, 0);
    }
    __syncthreads();
    float acc[R];
#pragma unroll
    for (int r = 0; r < R; ++r) acc[r] = 0.0f;
    const float4* wT = (const float4*)(BT + (size_t)j * HID);
#pragma unroll 2
    for (int kc = 0; kc < 8; ++kc) {
        float4 w0 = wT[kc * 4 + 0], w1 = wT[kc * 4 + 1];
        float4 w2 = wT[kc * 4 + 2], w3 = wT[kc * 4 + 3];
#pragma unroll
        for (int r = 0; r < R; ++r) {
            const float4* s4 = (const float4*)&sh[r * HID + kc * 16];
            acc[r] += dot4(s4[0], w0) + dot4(s4[1], w1) + dot4(s4[2], w2) + dot4(s4[3], w3);
        }
    }
    float bv = bias ? bias[j] : 0.0f;
#pragma unroll
    for (int r = 0; r < R; ++r) {
        int row = row0 + r;
        if (row < M) C[(long)row * NCOL + j] = acc[r] + bv;
    }
}

// ---------- in-place LayerNorm + GELU (+ optional t_emb[batch[row]]) ----------
__global__ __launch_bounds__(128, 4) void ln_gelu_kernel(
    float* __restrict__ X, const float* __restrict__ g,
    const float* __restrict__ bta,
    const float* __restrict__ t_emb, const int* __restrict__ batch) {
    int row = blockIdx.x, j = threadIdx.x;
    __shared__ float wred[2], wred2[2];
    int wave = j >> 6, lane = j & 63;
    float v = X[(long)row * HID + j];
    float s = wave_sum(v);
    if (lane == 0) wred[wave] = s;
    __syncthreads();
    float mean = (wred[0] + wred[1]) * (1.0f / HID);
    float d = v - mean;
    float s2 = wave_sum(d * d);
    if (lane == 0) wred2[wave] = s2;
    __syncthreads();
    float var = (wred2[0] + wred2[1]) * (1.0f / HID);
    float y = gelu_f(d * rsqrtf(var + LN_EPS) * g[j] + bta[j]);
    if (t_emb) y += t_emb[batch[row] * HID + j];
    X[(long)row * HID + j] = y;
}

// ---------- fused: edge-encode + segment-sum into loop_sum/cnt ----------
template <int R>
__global__ __launch_bounds__(128, 4) void edge_enc_loop_kernel(
    const float* __restrict__ edge_attr,
    const float* __restrict__ eWT, /* [128][32] */
    const float* __restrict__ eb,
    const float* __restrict__ eg, const float* __restrict__ ebe,
    const int* __restrict__ ei_dst,
    float* __restrict__ loop_sum, float* __restrict__ cnt) {
    __shared__ __align__(16) float sattr[R * EDGE_IN];
    __shared__ float wred[2][R], wred2[2][R];
    __shared__ int sdst[R];
    int j = threadIdx.x;
    int wave = j >> 6, lane = j & 63;
    long e0 = (long)blockIdx.x * R;
    if (j < R * 8) {
        long q = e0 * 8 + j;  // float4 index into edge_attr
        if (q < (long)N_EDGES * 8) ((float4*)sattr)[j] = ((const float4*)edge_attr)[q];
    }
    if (j < R) {
        long e = e0 + j;
        if (e < N_EDGES) sdst[j] = ei_dst[e];
    }
    __syncthreads();
    // eW^T row j in registers (32 floats)
    const float4* ewr = (const float4*)(eWT + (size_t)j * EDGE_IN);
    float4 ew[8];
#pragma unroll
    for (int q = 0; q < 8; ++q) ew[q] = ewr[q];
    float ebj = eb[j];
    float val[R];
#pragma unroll
    for (int r = 0; r < R; ++r) {
        float v = ebj;
        const float4* a4 = (const float4*)&sattr[r * EDGE_IN];
#pragma unroll
        for (int q = 0; q < 8; ++q) v += dot4(a4[q], ew[q]);
        val[r] = v;
    }
    // LN over 128 threads
#pragma unroll
    for (int r = 0; r < R; ++r) {
        float s = wave_sum(val[r]);
        if (lane == 0) wred[wave][r] = s;
    }
    __syncthreads();
    float mean[R];
#pragma unroll
    for (int r = 0; r < R; ++r) mean[r] = (wred[0][r] + wred[1][r]) * (1.0f / HID);
#pragma unroll
    for (int r = 0; r < R; ++r) {
        float d = val[r] - mean[r];
        float s = wave_sum(d * d);
        if (lane == 0) wred2[wave][r] = s;
    }
    __syncthreads();
    float egj = eg[j], ebej = ebe[j];
#pragma unroll
    for (int r = 0; r < R; ++r) {
        long e = e0 + r;
        if (e >= N_EDGES) break;
        float var = (wred2[0][r] + wred2[1][r]) * (1.0f / HID);
        float y = gelu_f((val[r] - mean[r]) * rsqrtf(var + LN_EPS) * egj + ebej);
        int d = sdst[r];
        atomicAdd(&loop_sum[(long)d * HID + j], y);
        if (j == 0) atomicAdd(&cnt[d], 1.0f);
    }
}

__global__ void loop_div_kernel(float* __restrict__ loop_attr, const float* __restrict__ cnt) {
    int idx = blockIdx.x * blockDim.x + threadIdx.x;
    if (idx >= N_NODES * HID) return;
    int n = idx >> 7;
    loop_attr[idx] = loop_attr[idx] / fmaxf(cnt[n], 1.0f);
}

// ---------- init mx=-inf, den=0 ----------
__global__ void init_mx_den_kernel(float* __restrict__ mx, float* __restrict__ den) {
    int idx = blockIdx.x * blockDim.x + threadIdx.x;
    if (idx >= N_NODES * HEADS) return;
    mx[idx] = -INFINITY;
    den[idx] = 0.0f;
}

// ---------- fused: edge-encode recompute + em-GEMM + leakyrelu + logit + atomicMax ----------
template <int R>
__global__ __launch_bounds__(128, 4) void att_logit_kernel(
    const float* __restrict__ edge_attr,
    const float* __restrict__ eWT, /* [128][32] */
    const float* __restrict__ eb,
    const float* __restrict__ eg, const float* __restrict__ ebe,
    const float* __restrict__ loop_attr,
    const float* __restrict__ cWeT_l, /* [128][128] (transposed) */
    const float* __restrict__ catt_l, /* [128] */
    const float* __restrict__ xl, const float* __restrict__ xr,
    const int* __restrict__ ei_src, const int* __restrict__ ei_dst,
    float* __restrict__ logit, float* __restrict__ mx) {
    __shared__ __align__(16) float sh[R * HID];
    __shared__ __align__(16) float sattr[R * EDGE_IN];
    __shared__ float wred[2][R], wred2[2][R];
    __shared__ int ssrc[R], sdst[R];
    int j = threadIdx.x;
    int wave = j >> 6, lane = j & 63;
    long e0 = (long)blockIdx.x * R;
    bool real_block = (e0 < N_EDGES);  // blocks never straddle (N_EDGES % R == 0)
    if (real_block && j < R * 8) {
        long q = e0 * 8 + j;
        if (q < (long)N_EDGES * 8) ((float4*)sattr)[j] = ((const float4*)edge_attr)[q];
    }
    if (j < R) {
        long e = e0 + j;
        if (e < EF) {
            if (e < N_EDGES) { ssrc[j] = ei_src[e]; sdst[j] = ei_dst[e]; }
            else             { ssrc[j] = sdst[j] = (int)(e - N_EDGES); }
        }
    }
    __syncthreads();
    if (real_block) {
        float val[R];
        const float4* ewr = (const float4*)(eWT + (size_t)j * EDGE_IN);
        float4 ew[8];
#pragma unroll
        for (int q = 0; q < 8; ++q) ew[q] = ewr[q];
        float ebj = eb[j];
#pragma unroll
        for (int r = 0; r < R; ++r) {
            float v = ebj;
            const float4* a4 = (const float4*)&sattr[r * EDGE_IN];
#pragma unroll
            for (int q = 0; q < 8; ++q) v += dot4(a4[q], ew[q]);
            val[r] = v;
        }
        // LN over the 128 columns
#pragma unroll
        for (int r = 0; r < R; ++r) {
            float s = wave_sum(val[r]);
            if (lane == 0) wred[wave][r] = s;
        }
        __syncthreads();
        float mean[R];
#pragma unroll
        for (int r = 0; r < R; ++r) mean[r] = (wred[0][r] + wred[1][r]) * (1.0f / HID);
#pragma unroll
        for (int r = 0; r < R; ++r) {
            float d = val[r] - mean[r];
            float s = wave_sum(d * d);
            if (lane == 0) wred2[wave][r] = s;
        }
        __syncthreads();
        float egj = eg[j], ebej = ebe[j];
#pragma unroll
        for (int r = 0; r < R; ++r) {
            float var = (wred2[0][r] + wred2[1][r]) * (1.0f / HID);
            sh[r * HID + j] = gelu_f((val[r] - mean[r]) * rsqrtf(var + LN_EPS) * egj + ebej);
        }
    } else {
        // self-loop rows: loop_attr is already the final ea row
#pragma unroll
        for (int r = 0; r < R; ++r) {
            long e = e0 + r;
            sh[r * HID + j] = (e < EF) ? loop_attr[(long)(e - N_EDGES) * HID + j] : 0.0f;
        }
    }
    __syncthreads();
    // em GEMM: acc[r] = dot(sh_row_r, cWeT_row_j)
    float acc[R];
#pragma unroll
    for (int r = 0; r < R; ++r) acc[r] = 0.0f;
    const float4* wT = (const float4*)(cWeT_l + (size_t)j * HID);
#pragma unroll 2
    for (int kc = 0; kc < 8; ++kc) {
        float4 w0 = wT[kc * 4 + 0], w1 = wT[kc * 4 + 1];
        float4 w2 = wT[kc * 4 + 2], w3 = wT[kc * 4 + 3];
#pragma unroll
        for (int r = 0; r < R; ++r) {
            const float4* s4 = (const float4*)&sh[r * HID + kc * 16];
            acc[r] += dot4(s4[0], w0) + dot4(s4[1], w1) + dot4(s4[2], w2) + dot4(s4[3], w3);
        }
    }
    float cj = catt_l[j];
    int head = j >> 4;
    for (int r = 0; r < R; ++r) {
        long e = e0 + r;
        if (e >= EF) break;
        int s = ssrc[r], d = sdst[r];
        float m = xl[(long)s * HID + j] + xr[(long)d * HID + j] + acc[r];
        m = (m > 0.0f) ? m : 0.2f * m;
        float p = m * cj;
        p += __shfl_down(p, 8, 16);
        p += __shfl_down(p, 4, 16);
        p += __shfl_down(p, 2, 16);
        p += __shfl_down(p, 1, 16);
        if ((j & 15) == 0) {
            logit[e * HEADS + head] = p;
            atomicMaxF(&mx[(long)d * HEADS + head], p);
        }
    }
}

// ---------- exp(logit-mx), accumulate denominator ----------
__global__ void softmax_norm_kernel(const int* __restrict__ ei_dst, const float* __restrict__ mx,
                                    float* __restrict__ logit, float* __restrict__ den) {
    long idx = (long)blockIdx.x * blockDim.x + threadIdx.x;
    if (idx >= (long)EF * HEADS) return;
    long e = idx >> 3;
    int hh = (int)(idx & 7);
    int d = (e < N_EDGES) ? ei_dst[e] : (int)(e - N_EDGES);
    float ex = expf(logit[idx] - mx[(long)d * HEADS + hh]);
    logit[idx] = ex;
    atomicAdd(&den[(long)d * HEADS + hh], ex);
}

// ---------- alpha-weighted aggregation (float4: 4 cols/thread) ----------
__global__ void aggregate_kernel(const float* __restrict__ logit, const float* __restrict__ den,
                                 const float* __restrict__ xl,
                                 const int* __restrict__ ei_src, const int* __restrict__ ei_dst,
                                 float* __restrict__ aggout) {
    long idx = (long)blockIdx.x * blockDim.x + threadIdx.x;
    if (idx >= (long)EF * 32) return;
    long e = idx >> 5;
    int q = (int)(idx & 31);  // 4-col group
    int j0 = q << 2;
    int head = q >> 2;
    int s, d;
    if (e < N_EDGES) { s = ei_src[e]; d = ei_dst[e]; }
    else             { s = d = (int)(e - N_EDGES); }
    float alpha = logit[e * HEADS + head] / (den[(long)d * HEADS + head] + 1e-16f);
    float4 xv = *(const float4*)&xl[(long)s * HID + j0];
    float* dst = &aggout[(long)d * HID + j0];
    atomicAdd(dst + 0, alpha * xv.x);
    atomicAdd(dst + 1, alpha * xv.y);
    atomicAdd(dst + 2, alpha * xv.z);
    atomicAdd(dst + 3, alpha * xv.w);
}

// ---------- h = gelu(aggout + cbias) + h ----------
__global__ void residual_kernel(const float* __restrict__ aggout, const float* __restrict__ cbias_l,
                                float* __restrict__ h) {
    int idx = blockIdx.x * blockDim.x + threadIdx.x;
    if (idx >= N_NODES * HID) return;
    int j = idx & 127;
    h[idx] = gelu_f(aggout[idx] + cbias_l[j]) + h[idx];
}

// ---------- pooling ----------
#define POOL_NODES 64
__global__ __launch_bounds__(128, 4) void pool_kernel(
    const float* __restrict__ h, const int* __restrict__ batch,
    float* __restrict__ gsum, float* __restrict__ gcnt) {
    __shared__ float acc[N_GRAPHS][HID];
    __shared__ float cnt_sh[N_GRAPHS];
    int j = threadIdx.x;
    for (int g = 0; g < N_GRAPHS; ++g) acc[g][j] = 0.0f;
    if (j < N_GRAPHS) cnt_sh[j] = 0.0f;
    __syncthreads();
    int n0 = blockIdx.x * POOL_NODES;
    for (int i = 0; i < POOL_NODES; ++i) {
        int n = n0 + i;
        if (n >= N_NODES) break;
        int g = batch[n];
        acc[g][j] += h[(long)n * HID + j];
        if (j == 0) cnt_sh[g] += 1.0f;
    }
    __syncthreads();
    for (int g = 0; g < N_GRAPHS; ++g) atomicAdd(&gsum[g * HID + j], acc[g][j]);
    if (j < N_GRAPHS) atomicAdd(&gcnt[j], cnt_sh[j]);
}

// ---------- props head ----------
__global__ __launch_bounds__(128, 4) void props_kernel(
    const float* __restrict__ gsum, const float* __restrict__ gcnt,
    const float* __restrict__ pW1, const float* __restrict__ pb1,
    const float* __restrict__ pg, const float* __restrict__ pbe,
    const float* __restrict__ pW2, const float* __restrict__ pb2,
    float* __restrict__ out_props) {
    int g = blockIdx.x, j = threadIdx.x;
    __shared__ float feat[HID], red[HID], t2[HID];
    float c = fmaxf(gcnt[g], 1.0f);
    feat[j] = gsum[g * HID + j] / c;
    __syncthreads();
    float acc = pb1[j];
    for (int k = 0; k < HID; ++k) acc += feat[k] * pW1[k * HID + j];
    red[j] = acc;
    __syncthreads();
    for (int s = 64; s > 0; s >>= 1) { if (j < s) red[j] += red[j + s]; __syncthreads(); }
    float mean = red[0] * (1.0f / HID);
    __syncthreads();
    float dd = acc - mean;
    red[j] = dd * dd;
    __syncthreads();
    for (int s = 64; s > 0; s >>= 1) { if (j < s) red[j] += red[j + s]; __syncthreads(); }
    float var = red[0] * (1.0f / HID);
    t2[j] = gelu_f(dd * rsqrtf(var + LN_EPS) * pg[j] + pbe[j]);
    __syncthreads();
    if (j < COND) {
        float a = pb2[j];
        for (int k = 0; k < HID; ++k) a += t2[k] * pW2[k * COND + j];
        out_props[g * COND + j] = a;
    }
}

extern "C" void kernel_launch(void* const* d_in, const int* in_sizes, int n_in,
                              void* d_out, int out_size, void* d_ws, size_t ws_size,
                              hipStream_t stream) {
    const float* x        = (const float*)d_in[0];
    const float* edge_attr= (const float*)d_in[1];
    const float* t        = (const float*)d_in[2];
    const float* conds    = (const float*)d_in[3];
    const float* tW1      = (const float*)d_in[4];
    const float* tb1      = (const float*)d_in[5];
    const float* tW2      = (const float*)d_in[6];
    const float* tb2      = (const float*)d_in[7];
    const float* encW     = (const float*)d_in[8];
    const float* encb     = (const float*)d_in[9];
    const float* encg     = (const float*)d_in[10];
    const float* encbe    = (const float*)d_in[11];
    const float* eW       = (const float*)d_in[12];
    const float* eb       = (const float*)d_in[13];
    const float* eg       = (const float*)d_in[14];
    const float* ebe      = (const float*)d_in[15];
    const float* cWl      = (const float*)d_in[16];
    const float* cbl      = (const float*)d_in[17];
    const float* cWr      = (const float*)d_in[18];
    const float* cbr      = (const float*)d_in[19];
    const float* cWe      = (const float*)d_in[20];
    const float* catt     = (const float*)d_in[21];
    const float* cbias    = (const float*)d_in[22];
    const float* nW1      = (const float*)d_in[23];
    const float* nb1      = (const float*)d_in[24];
    const float* ng       = (const float*)d_in[25];
    const float* nbe      = (const float*)d_in[26];
    const float* nW2      = (const float*)d_in[27];
    const float* nb2      = (const float*)d_in[28];
    const float* pW1      = (const float*)d_in[29];
    const float* pb1      = (const float*)d_in[30];
    const float* pg       = (const float*)d_in[31];
    const float* pbe      = (const float*)d_in[32];
    const float* pW2      = (const float*)d_in[33];
    const float* pb2      = (const float*)d_in[34];
    const int* edge_index = (const int*)d_in[35];
    const int* batch      = (const int*)d_in[36];
    const int* ei_src = edge_index;
    const int* ei_dst = edge_index + N_EDGES;

    // workspace layout (~95 MB of f32)
    float* ws = (float*)d_ws;
    size_t off = 0;
    auto alloc = [&](size_t n) { float* p = ws + off; off += n; return p; };
    float* t_emb     = alloc((size_t)N_GRAPHS * HID);
    float* h         = alloc((size_t)N_NODES * HID);
    float* loop_attr = alloc((size_t)N_NODES * HID);
    float* cnt       = alloc((size_t)N_NODES);
    float* xl        = alloc((size_t)N_NODES * HID);
    float* xr        = alloc((size_t)N_NODES * HID);
    float* logit     = alloc((size_t)EF * HEADS);      // 4.08M floats
    float* mx        = alloc((size_t)N_NODES * HEADS);
    float* den       = alloc((size_t)N_NODES * HEADS);
    float* aggout    = alloc((size_t)N_NODES * HID);
    float* gsum      = alloc((size_t)N_GRAPHS * HID);
    float* gcnt      = alloc((size_t)N_GRAPHS);
    float* wT12      = alloc((size_t)12 * 16384);      // cWlT[4] | cWrT[4] | cWeT[4]
    float* eWT       = alloc((size_t)HID * EDGE_IN);
    float* nW1T      = alloc((size_t)HID * HID);
    float* nW2T      = alloc((size_t)NODE_OUT * HID);
    // aliases (disjoint lifetimes):
    float* xc   = logit;  // [N,72] pre-layer only; logit is bigger
    float* tmp1 = xl;     // post-layer only
    (void)ws_size; (void)in_sizes; (void)n_in; (void)out_size;

    float* pred_noise = (float*)d_out;                              // [N,64]
    float* pred_props = (float*)d_out + (size_t)N_NODES * NODE_OUT; // [16,8]

    // 0. weight transposes
    hipLaunchKernelGGL(batched_transpose12_kernel, dim3((12 * 16384 + 255) / 256), dim3(256), 0,
                       stream, cWl, cWr, cWe, wT12);
    hipLaunchKernelGGL(transpose_kernel, dim3((EDGE_IN * HID + 255) / 256), dim3(256), 0, stream,
                       eW, eWT, EDGE_IN, HID);
    hipLaunchKernelGGL(transpose_kernel, dim3((HID * HID + 255) / 256), dim3(256), 0, stream,
                       nW1, nW1T, HID, HID);
    hipLaunchKernelGGL(transpose_kernel, dim3((HID * NODE_OUT + 255) / 256), dim3(256), 0, stream,
                       nW2, nW2T, HID, NODE_OUT);

    // 1. time MLP
    hipLaunchKernelGGL(time_mlp_kernel, dim3(N_GRAPHS), dim3(HID), 0, stream,
                       t, tW1, tb1, tW2, tb2, t_emb);
    // 2. concat
    hipLaunchKernelGGL(concat_kernel, dim3((N_NODES * 72 + 255) / 256), dim3(256), 0, stream,
                       x, conds, batch, xc);
    // 3. node encoder gemm + LN/GELU (+t_emb[batch])
    hipLaunchKernelGGL((gemm_kernel<HID, 8>), dim3(N_NODES / 8), dim3(HID), 0, stream,
                       xc, encW, encb, h, N_NODES, 72);
    hipLaunchKernelGGL(ln_gelu_kernel, dim3(N_NODES), dim3(HID), 0, stream,
                       h, encg, encbe, t_emb, batch);
    // 4. self-loop attr = segment-mean of encoded edge_attr over dst (encode fused)
    hipLaunchKernelGGL(zero_kernel, dim3(1024), dim3(256), 0, stream,
                       loop_attr, (long)N_NODES * HID);
    hipLaunchKernelGGL(zero_kernel, dim3(64), dim3(256), 0, stream, cnt, (long)N_NODES);
    hipLaunchKernelGGL((edge_enc_loop_kernel<8>), dim3(N_EDGES / 8), dim3(HID), 0, stream,
                       edge_attr, eWT, eb, eg, ebe, ei_dst, loop_attr, cnt);
    hipLaunchKernelGGL(loop_div_kernel, dim3((N_NODES * HID + 255) / 256), dim3(256), 0, stream,
                       loop_attr, cnt);

    // 5. layers
    for (int l = 0; l < NLAYERS; ++l) {
        const float* cWlT_l = wT12 + (size_t)l * 16384;
        const float* cWrT_l = wT12 + (size_t)(4 + l) * 16384;
        const float* cWeT_l = wT12 + (size_t)(8 + l) * 16384;
        const float* cbl_l = cbl + (size_t)l * HID;
        const float* cbr_l = cbr + (size_t)l * HID;
        const float* catt_l = catt + (size_t)l * HID;
        const float* cbias_l = cbias + (size_t)l * HID;

        hipLaunchKernelGGL((gemm_t_kernel<HID, 8>), dim3(N_NODES / 8), dim3(HID), 0, stream,
                           h, cWlT_l, cbl_l, xl, N_NODES);
        hipLaunchKernelGGL((gemm_t_kernel<HID, 8>), dim3(N_NODES / 8), dim3(HID), 0, stream,
                           h, cWrT_l, cbr_l, xr, N_NODES);
        hipLaunchKernelGGL(init_mx_den_kernel, dim3((N_NODES * HEADS + 255) / 256), dim3(256), 0,
                           stream, mx, den);
        hipLaunchKernelGGL((att_logit_kernel<8>), dim3(EF / 8), dim3(HID), 0, stream,
                           edge_attr, eWT, eb, eg, ebe, loop_attr,
                           cWeT_l, catt_l, xl, xr, ei_src, ei_dst, logit, mx);
        hipLaunchKernelGGL(softmax_norm_kernel,
                           dim3((int)(((long)EF * HEADS + 255) / 256)), dim3(256), 0, stream,
                           ei_dst, mx, logit, den);
        hipLaunchKernelGGL(zero_kernel, dim3(1024), dim3(256), 0, stream,
                           aggout, (long)N_NODES * HID);
        hipLaunchKernelGGL(aggregate_kernel,
                           dim3((int)(((long)EF * 32 + 255) / 256)), dim3(256), 0, stream,
                           logit, den, xl, ei_src, ei_dst, aggout);
        hipLaunchKernelGGL(residual_kernel, dim3((N_NODES * HID + 255) / 256), dim3(256), 0, stream,
                           aggout, cbias_l, h);
    }

    // 6. noise head
    hipLaunchKernelGGL((gemm_t_kernel<HID, 8>), dim3(N_NODES / 8), dim3(HID), 0, stream,
                       h, nW1T, nb1, tmp1, N_NODES);
    hipLaunchKernelGGL(ln_gelu_kernel, dim3(N_NODES), dim3(HID), 0, stream,
                       tmp1, ng, nbe, (const float*)nullptr, (const int*)nullptr);
    hipLaunchKernelGGL((gemm_t_kernel<NODE_OUT, 8>), dim3(N_NODES / 8), dim3(NODE_OUT), 0, stream,
                       tmp1, nW2T, nb2, pred_noise, N_NODES);

    // 7. pooling + props head
    hipLaunchKernelGGL(zero_kernel, dim3(4), dim3(256), 0, stream,
                       gsum, (long)N_GRAPHS * HID);
    hipLaunchKernelGGL(zero_kernel, dim3(1), dim3(64), 0, stream, gcnt, (long)N_GRAPHS);
    hipLaunchKernelGGL(pool_kernel, dim3((N_NODES + POOL_NODES - 1) / POOL_NODES), dim3(HID), 0,
                       stream, h, batch, gsum, gcnt);
    hipLaunchKernelGGL(props_kernel, dim3(N_GRAPHS), dim3(HID), 0, stream,
                       gsum, gcnt, pW1, pb1, pg, pbe, pW2, pb2, pred_props);
}

// Round 5
// 12853.284 us; speedup vs baseline: 1.0454x; 1.0454x over previous
//
#include <hip/hip_runtime.h>
#include <math.h>

#define N_NODES 30000
#define N_EDGES 480000
#define N_GRAPHS 16
#define HID 128
#define HEADS 8
#define HEAD_DIM 16
#define NODE_IN 64
#define EDGE_IN 32
#define COND 8
#define NODE_OUT 64
#define NLAYERS 4
#define EF (N_EDGES + N_NODES) /* 510000; EF%8==0, N_EDGES%8==0, N_NODES%8==0 */
#define LN_EPS 1e-5f

__device__ __forceinline__ float gelu_f(float x) {
    return 0.5f * x * (1.0f + erff(x * 0.70710678118654752440f));
}

__device__ __forceinline__ float dot4(float4 a, float4 b) {
    return a.x * b.x + a.y * b.y + a.z * b.z + a.w * b.w;
}

__device__ __forceinline__ void atomicMaxF(float* addr, float val) {
    if (val >= 0.0f) {
        atomicMax((int*)addr, __float_as_int(val));
    } else {
        atomicMin((unsigned int*)addr, __float_as_uint(val));
    }
}

// wave(64)-wide sum; all lanes end with the sum
__device__ __forceinline__ float wave_sum(float s) {
    s += __shfl_xor(s, 1);
    s += __shfl_xor(s, 2);
    s += __shfl_xor(s, 4);
    s += __shfl_xor(s, 8);
    s += __shfl_xor(s, 16);
    s += __shfl_xor(s, 32);
    return s;
}

// ---------- generic zero ----------
__global__ void zero_kernel(float* __restrict__ p, long n) {
    long i = (long)blockIdx.x * blockDim.x + threadIdx.x;
    long stride = (long)gridDim.x * blockDim.x;
    for (; i < n; i += stride) p[i] = 0.0f;
}

// ---------- transposes ----------
__global__ void transpose_kernel(const float* __restrict__ in, float* __restrict__ out,
                                 int K, int N) {
    int idx = blockIdx.x * blockDim.x + threadIdx.x;
    if (idx >= K * N) return;
    int k = idx / N, j = idx - k * N;
    out[j * K + k] = in[idx];
}

// 12 matrices of 128x128: cWl[0..3], cWr[0..3], cWe[0..3]
__global__ void batched_transpose12_kernel(const float* __restrict__ cWl,
                                           const float* __restrict__ cWr,
                                           const float* __restrict__ cWe,
                                           float* __restrict__ out) {
    int idx = blockIdx.x * blockDim.x + threadIdx.x;
    if (idx >= 12 * 16384) return;
    int m = idx >> 14;
    int r = idx & 16383;
    int k = r >> 7, j = r & 127;
    const float* base = (m < 4) ? (cWl + (size_t)m * 16384)
                      : (m < 8) ? (cWr + (size_t)(m - 4) * 16384)
                                : (cWe + (size_t)(m - 8) * 16384);
    out[(size_t)m * 16384 + j * 128 + k] = base[r];
}

// ---------- time MLP: t[16] -> t_emb[16,128] ----------
__global__ __launch_bounds__(128) void time_mlp_kernel(
    const float* __restrict__ t,
    const float* __restrict__ tW1, const float* __restrict__ tb1,
    const float* __restrict__ tW2, const float* __restrict__ tb2,
    float* __restrict__ t_emb) {
    __shared__ float hsh[HID];
    int b = blockIdx.x, j = threadIdx.x;
    float tv = t[b];
    hsh[j] = gelu_f(tv * tW1[j] + tb1[j]);
    __syncthreads();
    float acc = tb2[j];
    for (int k = 0; k < HID; ++k) acc += hsh[k] * tW2[k * HID + j];
    t_emb[b * HID + j] = acc;
}

// ---------- concat x(64) + conditions[batch](8) -> xc[N,72] ----------
__global__ void concat_kernel(const float* __restrict__ x, const float* __restrict__ cond,
                              const int* __restrict__ batch, float* __restrict__ xc) {
    int idx = blockIdx.x * blockDim.x + threadIdx.x;
    if (idx >= N_NODES * 72) return;
    int n = idx / 72, c = idx % 72;
    xc[idx] = (c < NODE_IN) ? x[n * NODE_IN + c] : cond[batch[n] * COND + (c - NODE_IN)];
}

// ---------- generic GEMM (used only for the K=72 encoder) ----------
template <int NCOL, int R>
__global__ __launch_bounds__(128) void gemm_kernel(
    const float* __restrict__ A, const float* __restrict__ B,
    const float* __restrict__ bias, float* __restrict__ C,
    int M, int K) {
    __shared__ float sh[R * HID];
    int j = threadIdx.x;
    int row0 = blockIdx.x * R;
    int total = R * K;
    for (int i = j; i < total; i += NCOL) {
        int r = i / K, k = i - r * K;
        sh[r * K + k] = A[(long)(row0 + r) * K + k];
    }
    __syncthreads();
    float acc[R];
    float bv = bias ? bias[j] : 0.0f;
#pragma unroll
    for (int r = 0; r < R; ++r) acc[r] = bv;
    for (int k = 0; k < K; ++k) {
        float w = B[k * NCOL + j];
#pragma unroll
        for (int r = 0; r < R; ++r) acc[r] += sh[r * K + k] * w;
    }
#pragma unroll
    for (int r = 0; r < R; ++r) C[(long)(row0 + r) * NCOL + j] = acc[r];
}

// ---------- GEMM with transposed B, K=128 (M % R == 0 assumed) ----------
template <int NCOL, int R>
__global__ __launch_bounds__(128) void gemm_t_kernel(
    const float* __restrict__ A, const float* __restrict__ BT,
    const float* __restrict__ bias, float* __restrict__ C, int M) {
    __shared__ __align__(16) float sh[R * HID];
    int j = threadIdx.x;
    int row0 = blockIdx.x * R;
    const float4* A4 = (const float4*)A;
    float4* sh4 = (float4*)sh;
    for (int i = j; i < R * 32; i += NCOL) {
        sh4[i] = A4[(long)row0 * 32 + i];
    }
    __syncthreads();
    float acc[R];
#pragma unroll
    for (int r = 0; r < R; ++r) acc[r] = 0.0f;
    const float4* wT = (const float4*)(BT + (size_t)j * HID);
#pragma unroll 1
    for (int kc = 0; kc < 8; ++kc) {
        float4 w0 = wT[kc * 4 + 0], w1 = wT[kc * 4 + 1];
        float4 w2 = wT[kc * 4 + 2], w3 = wT[kc * 4 + 3];
#pragma unroll
        for (int r = 0; r < R; ++r) {
            const float4* s4 = (const float4*)&sh[r * HID + kc * 16];
            acc[r] += dot4(s4[0], w0) + dot4(s4[1], w1) + dot4(s4[2], w2) + dot4(s4[3], w3);
        }
    }
    float bv = bias ? bias[j] : 0.0f;
#pragma unroll
    for (int r = 0; r < R; ++r) {
        C[(long)(row0 + r) * NCOL + j] = acc[r] + bv;
    }
}

// ---------- in-place LayerNorm + GELU (+ optional t_emb[batch[row]]) ----------
__global__ __launch_bounds__(128) void ln_gelu_kernel(
    float* __restrict__ X, const float* __restrict__ g,
    const float* __restrict__ bta,
    const float* __restrict__ t_emb, const int* __restrict__ batch) {
    int row = blockIdx.x, j = threadIdx.x;
    __shared__ float wred[2], wred2[2];
    int wave = j >> 6, lane = j & 63;
    float v = X[(long)row * HID + j];
    float s = wave_sum(v);
    if (lane == 0) wred[wave] = s;
    __syncthreads();
    float mean = (wred[0] + wred[1]) * (1.0f / HID);
    float d = v - mean;
    float s2 = wave_sum(d * d);
    if (lane == 0) wred2[wave] = s2;
    __syncthreads();
    float var = (wred2[0] + wred2[1]) * (1.0f / HID);
    float y = gelu_f(d * rsqrtf(var + LN_EPS) * g[j] + bta[j]);
    if (t_emb) y += t_emb[batch[row] * HID + j];
    X[(long)row * HID + j] = y;
}

// ---------- fused: edge-encode + segment-sum into loop_sum/cnt ----------
// N_EDGES % R == 0: no tail handling anywhere.
template <int R>
__global__ __launch_bounds__(128) void edge_enc_loop_kernel(
    const float* __restrict__ edge_attr,
    const float* __restrict__ eWT, /* [128][32] */
    const float* __restrict__ eb,
    const float* __restrict__ eg, const float* __restrict__ ebe,
    const int* __restrict__ ei_dst,
    float* __restrict__ loop_sum, float* __restrict__ cnt) {
    __shared__ __align__(16) float sattr[R * EDGE_IN];
    __shared__ float wred[2][R], wred2[2][R];
    __shared__ int sdst[R];
    int j = threadIdx.x;
    int wave = j >> 6, lane = j & 63;
    long e0 = (long)blockIdx.x * R;
    if (j < R * 8) ((float4*)sattr)[j] = ((const float4*)edge_attr)[e0 * 8 + j];
    if (j < R) sdst[j] = ei_dst[e0 + j];
    __syncthreads();
    float val[R];
    float ebj = eb[j];
#pragma unroll
    for (int r = 0; r < R; ++r) val[r] = ebj;
    const float4* ewr = (const float4*)(eWT + (size_t)j * EDGE_IN);
#pragma unroll
    for (int q = 0; q < 8; ++q) {
        float4 wq = ewr[q];
#pragma unroll
        for (int r = 0; r < R; ++r) {
            float4 a = *(const float4*)&sattr[r * EDGE_IN + q * 4];
            val[r] += dot4(a, wq);
        }
    }
#pragma unroll
    for (int r = 0; r < R; ++r) {
        float s = wave_sum(val[r]);
        if (lane == 0) wred[wave][r] = s;
    }
    __syncthreads();
#pragma unroll
    for (int r = 0; r < R; ++r) {
        float mean = (wred[0][r] + wred[1][r]) * (1.0f / HID);
        float d = val[r] - mean;
        val[r] = d;
        float s = wave_sum(d * d);
        if (lane == 0) wred2[wave][r] = s;
    }
    __syncthreads();
    float egj = eg[j], ebej = ebe[j];
#pragma unroll
    for (int r = 0; r < R; ++r) {
        float var = (wred2[0][r] + wred2[1][r]) * (1.0f / HID);
        float y = gelu_f(val[r] * rsqrtf(var + LN_EPS) * egj + ebej);
        int d = sdst[r];
        atomicAdd(&loop_sum[(long)d * HID + j], y);
        if (j == 0) atomicAdd(&cnt[d], 1.0f);
    }
}

__global__ void loop_div_kernel(float* __restrict__ loop_attr, const float* __restrict__ cnt) {
    int idx = blockIdx.x * blockDim.x + threadIdx.x;
    if (idx >= N_NODES * HID) return;
    int n = idx >> 7;
    loop_attr[idx] = loop_attr[idx] / fmaxf(cnt[n], 1.0f);
}

// ---------- init mx=-inf, den=0 ----------
__global__ void init_mx_den_kernel(float* __restrict__ mx, float* __restrict__ den) {
    int idx = blockIdx.x * blockDim.x + threadIdx.x;
    if (idx >= N_NODES * HEADS) return;
    mx[idx] = -INFINITY;
    den[idx] = 0.0f;
}

// ---------- fused: edge-encode recompute + em-GEMM + leakyrelu + logit + atomicMax ----------
// EF % R == 0 and N_EDGES % R == 0: blocks are full and never straddle the boundary.
template <int R>
__global__ __launch_bounds__(128) void att_logit_kernel(
    const float* __restrict__ edge_attr,
    const float* __restrict__ eWT, /* [128][32] */
    const float* __restrict__ eb,
    const float* __restrict__ eg, const float* __restrict__ ebe,
    const float* __restrict__ loop_attr,
    const float* __restrict__ cWeT_l, /* [128][128] (transposed) */
    const float* __restrict__ catt_l, /* [128] */
    const float* __restrict__ xl, const float* __restrict__ xr,
    const int* __restrict__ ei_src, const int* __restrict__ ei_dst,
    float* __restrict__ logit, float* __restrict__ mx) {
    __shared__ __align__(16) float sh[R * HID];
    __shared__ __align__(16) float sattr[R * EDGE_IN];
    __shared__ float wred[2][R], wred2[2][R];
    __shared__ int ssrc[R], sdst[R];
    int j = threadIdx.x;
    int wave = j >> 6, lane = j & 63;
    long e0 = (long)blockIdx.x * R;
    bool real_block = (e0 < N_EDGES);
    if (real_block && j < R * 8) {
        ((float4*)sattr)[j] = ((const float4*)edge_attr)[e0 * 8 + j];
    }
    if (j < R) {
        long e = e0 + j;
        if (e < N_EDGES) { ssrc[j] = ei_src[e]; sdst[j] = ei_dst[e]; }
        else             { ssrc[j] = sdst[j] = (int)(e - N_EDGES); }
    }
    __syncthreads();
    if (real_block) {
        // edge-encode: val = edge_attr @ eW + eb   (q-outer: one weight float4 live)
        float val[R];
        float ebj = eb[j];
#pragma unroll
        for (int r = 0; r < R; ++r) val[r] = ebj;
        const float4* ewr = (const float4*)(eWT + (size_t)j * EDGE_IN);
#pragma unroll
        for (int q = 0; q < 8; ++q) {
            float4 wq = ewr[q];
#pragma unroll
            for (int r = 0; r < R; ++r) {
                float4 a = *(const float4*)&sattr[r * EDGE_IN + q * 4];
                val[r] += dot4(a, wq);
            }
        }
        // LN across the 128 columns
#pragma unroll
        for (int r = 0; r < R; ++r) {
            float s = wave_sum(val[r]);
            if (lane == 0) wred[wave][r] = s;
        }
        __syncthreads();
#pragma unroll
        for (int r = 0; r < R; ++r) {
            float mean = (wred[0][r] + wred[1][r]) * (1.0f / HID);
            float d = val[r] - mean;
            val[r] = d;
            float s = wave_sum(d * d);
            if (lane == 0) wred2[wave][r] = s;
        }
        __syncthreads();
        float egj = eg[j], ebej = ebe[j];
#pragma unroll
        for (int r = 0; r < R; ++r) {
            float var = (wred2[0][r] + wred2[1][r]) * (1.0f / HID);
            sh[r * HID + j] = gelu_f(val[r] * rsqrtf(var + LN_EPS) * egj + ebej);
        }
    } else {
        // self-loop rows: loop_attr is already the final ea row
#pragma unroll
        for (int r = 0; r < R; ++r) {
            sh[r * HID + j] = loop_attr[(long)(e0 + r - N_EDGES) * HID + j];
        }
    }
    __syncthreads();
    // em GEMM: acc[r] = dot(sh_row_r, cWeT_row_j)
    float acc[R];
#pragma unroll
    for (int r = 0; r < R; ++r) acc[r] = 0.0f;
    const float4* wT = (const float4*)(cWeT_l + (size_t)j * HID);
#pragma unroll 1
    for (int kc = 0; kc < 8; ++kc) {
        float4 w0 = wT[kc * 4 + 0], w1 = wT[kc * 4 + 1];
        float4 w2 = wT[kc * 4 + 2], w3 = wT[kc * 4 + 3];
#pragma unroll
        for (int r = 0; r < R; ++r) {
            const float4* s4 = (const float4*)&sh[r * HID + kc * 16];
            acc[r] += dot4(s4[0], w0) + dot4(s4[1], w1) + dot4(s4[2], w2) + dot4(s4[3], w3);
        }
    }
    float cj = catt_l[j];
    int head = j >> 4;
#pragma unroll
    for (int r = 0; r < R; ++r) {
        long e = e0 + r;
        int s = ssrc[r], d = sdst[r];
        float m = xl[(long)s * HID + j] + xr[(long)d * HID + j] + acc[r];
        m = (m > 0.0f) ? m : 0.2f * m;
        float p = m * cj;
        p += __shfl_down(p, 8, 16);
        p += __shfl_down(p, 4, 16);
        p += __shfl_down(p, 2, 16);
        p += __shfl_down(p, 1, 16);
        if ((j & 15) == 0) {
            logit[e * HEADS + head] = p;
            atomicMaxF(&mx[(long)d * HEADS + head], p);
        }
    }
}

// ---------- exp(logit-mx), accumulate denominator ----------
__global__ void softmax_norm_kernel(const int* __restrict__ ei_dst, const float* __restrict__ mx,
                                    float* __restrict__ logit, float* __restrict__ den) {
    long idx = (long)blockIdx.x * blockDim.x + threadIdx.x;
    if (idx >= (long)EF * HEADS) return;
    long e = idx >> 3;
    int hh = (int)(idx & 7);
    int d = (e < N_EDGES) ? ei_dst[e] : (int)(e - N_EDGES);
    float ex = expf(logit[idx] - mx[(long)d * HEADS + hh]);
    logit[idx] = ex;
    atomicAdd(&den[(long)d * HEADS + hh], ex);
}

// ---------- alpha-weighted aggregation (float4: 4 cols/thread) ----------
__global__ void aggregate_kernel(const float* __restrict__ logit, const float* __restrict__ den,
                                 const float* __restrict__ xl,
                                 const int* __restrict__ ei_src, const int* __restrict__ ei_dst,
                                 float* __restrict__ aggout) {
    long idx = (long)blockIdx.x * blockDim.x + threadIdx.x;
    if (idx >= (long)EF * 32) return;
    long e = idx >> 5;
    int q = (int)(idx & 31);  // 4-col group
    int j0 = q << 2;
    int head = q >> 2;
    int s, d;
    if (e < N_EDGES) { s = ei_src[e]; d = ei_dst[e]; }
    else             { s = d = (int)(e - N_EDGES); }
    float alpha = logit[e * HEADS + head] / (den[(long)d * HEADS + head] + 1e-16f);
    float4 xv = *(const float4*)&xl[(long)s * HID + j0];
    float* dst = &aggout[(long)d * HID + j0];
    atomicAdd(dst + 0, alpha * xv.x);
    atomicAdd(dst + 1, alpha * xv.y);
    atomicAdd(dst + 2, alpha * xv.z);
    atomicAdd(dst + 3, alpha * xv.w);
}

// ---------- h = gelu(aggout + cbias) + h ----------
__global__ void residual_kernel(const float* __restrict__ aggout, const float* __restrict__ cbias_l,
                                float* __restrict__ h) {
    int idx = blockIdx.x * blockDim.x + threadIdx.x;
    if (idx >= N_NODES * HID) return;
    int j = idx & 127;
    h[idx] = gelu_f(aggout[idx] + cbias_l[j]) + h[idx];
}

// ---------- pooling ----------
#define POOL_NODES 64
__global__ __launch_bounds__(128) void pool_kernel(
    const float* __restrict__ h, const int* __restrict__ batch,
    float* __restrict__ gsum, float* __restrict__ gcnt) {
    __shared__ float acc[N_GRAPHS][HID];
    __shared__ float cnt_sh[N_GRAPHS];
    int j = threadIdx.x;
    for (int g = 0; g < N_GRAPHS; ++g) acc[g][j] = 0.0f;
    if (j < N_GRAPHS) cnt_sh[j] = 0.0f;
    __syncthreads();
    int n0 = blockIdx.x * POOL_NODES;
    for (int i = 0; i < POOL_NODES; ++i) {
        int n = n0 + i;
        if (n >= N_NODES) break;
        int g = batch[n];
        acc[g][j] += h[(long)n * HID + j];
        if (j == 0) cnt_sh[g] += 1.0f;
    }
    __syncthreads();
    for (int g = 0; g < N_GRAPHS; ++g) atomicAdd(&gsum[g * HID + j], acc[g][j]);
    if (j < N_GRAPHS) atomicAdd(&gcnt[j], cnt_sh[j]);
}

// ---------- props head ----------
__global__ __launch_bounds__(128) void props_kernel(
    const float* __restrict__ gsum, const float* __restrict__ gcnt,
    const float* __restrict__ pW1, const float* __restrict__ pb1,
    const float* __restrict__ pg, const float* __restrict__ pbe,
    const float* __restrict__ pW2, const float* __restrict__ pb2,
    float* __restrict__ out_props) {
    int g = blockIdx.x, j = threadIdx.x;
    __shared__ float feat[HID], red[HID], t2[HID];
    float c = fmaxf(gcnt[g], 1.0f);
    feat[j] = gsum[g * HID + j] / c;
    __syncthreads();
    float acc = pb1[j];
    for (int k = 0; k < HID; ++k) acc += feat[k] * pW1[k * HID + j];
    red[j] = acc;
    __syncthreads();
    for (int s = 64; s > 0; s >>= 1) { if (j < s) red[j] += red[j + s]; __syncthreads(); }
    float mean = red[0] * (1.0f / HID);
    __syncthreads();
    float dd = acc - mean;
    red[j] = dd * dd;
    __syncthreads();
    for (int s = 64; s > 0; s >>= 1) { if (j < s) red[j] += red[j + s]; __syncthreads(); }
    float var = red[0] * (1.0f / HID);
    t2[j] = gelu_f(dd * rsqrtf(var + LN_EPS) * pg[j] + pbe[j]);
    __syncthreads();
    if (j < COND) {
        float a = pb2[j];
        for (int k = 0; k < HID; ++k) a += t2[k] * pW2[k * COND + j];
        out_props[g * COND + j] = a;
    }
}

extern "C" void kernel_launch(void* const* d_in, const int* in_sizes, int n_in,
                              void* d_out, int out_size, void* d_ws, size_t ws_size,
                              hipStream_t stream) {
    const float* x        = (const float*)d_in[0];
    const float* edge_attr= (const float*)d_in[1];
    const float* t        = (const float*)d_in[2];
    const float* conds    = (const float*)d_in[3];
    const float* tW1      = (const float*)d_in[4];
    const float* tb1      = (const float*)d_in[5];
    const float* tW2      = (const float*)d_in[6];
    const float* tb2      = (const float*)d_in[7];
    const float* encW     = (const float*)d_in[8];
    const float* encb     = (const float*)d_in[9];
    const float* encg     = (const float*)d_in[10];
    const float* encbe    = (const float*)d_in[11];
    const float* eW       = (const float*)d_in[12];
    const float* eb       = (const float*)d_in[13];
    const float* eg       = (const float*)d_in[14];
    const float* ebe      = (const float*)d_in[15];
    const float* cWl      = (const float*)d_in[16];
    const float* cbl      = (const float*)d_in[17];
    const float* cWr      = (const float*)d_in[18];
    const float* cbr      = (const float*)d_in[19];
    const float* cWe      = (const float*)d_in[20];
    const float* catt     = (const float*)d_in[21];
    const float* cbias    = (const float*)d_in[22];
    const float* nW1      = (const float*)d_in[23];
    const float* nb1      = (const float*)d_in[24];
    const float* ng       = (const float*)d_in[25];
    const float* nbe      = (const float*)d_in[26];
    const float* nW2      = (const float*)d_in[27];
    const float* nb2      = (const float*)d_in[28];
    const float* pW1      = (const float*)d_in[29];
    const float* pb1      = (const float*)d_in[30];
    const float* pg       = (const float*)d_in[31];
    const float* pbe      = (const float*)d_in[32];
    const float* pW2      = (const float*)d_in[33];
    const float* pb2      = (const float*)d_in[34];
    const int* edge_index = (const int*)d_in[35];
    const int* batch      = (const int*)d_in[36];
    const int* ei_src = edge_index;
    const int* ei_dst = edge_index + N_EDGES;

    // workspace layout (~95 MB of f32)
    float* ws = (float*)d_ws;
    size_t off = 0;
    auto alloc = [&](size_t n) { float* p = ws + off; off += n; return p; };
    float* t_emb     = alloc((size_t)N_GRAPHS * HID);
    float* h         = alloc((size_t)N_NODES * HID);
    float* loop_attr = alloc((size_t)N_NODES * HID);
    float* cnt       = alloc((size_t)N_NODES);
    float* xl        = alloc((size_t)N_NODES * HID);
    float* xr        = alloc((size_t)N_NODES * HID);
    float* logit     = alloc((size_t)EF * HEADS);      // 4.08M floats
    float* mx        = alloc((size_t)N_NODES * HEADS);
    float* den       = alloc((size_t)N_NODES * HEADS);
    float* aggout    = alloc((size_t)N_NODES * HID);
    float* gsum      = alloc((size_t)N_GRAPHS * HID);
    float* gcnt      = alloc((size_t)N_GRAPHS);
    float* wT12      = alloc((size_t)12 * 16384);      // cWlT[4] | cWrT[4] | cWeT[4]
    float* eWT       = alloc((size_t)HID * EDGE_IN);
    float* nW1T      = alloc((size_t)HID * HID);
    float* nW2T      = alloc((size_t)NODE_OUT * HID);
    // aliases (disjoint lifetimes):
    float* xc   = logit;  // [N,72] pre-layer only; logit is bigger
    float* tmp1 = xl;     // post-layer only
    (void)ws_size; (void)in_sizes; (void)n_in; (void)out_size;

    float* pred_noise = (float*)d_out;                              // [N,64]
    float* pred_props = (float*)d_out + (size_t)N_NODES * NODE_OUT; // [16,8]

    // 0. weight transposes
    hipLaunchKernelGGL(batched_transpose12_kernel, dim3((12 * 16384 + 255) / 256), dim3(256), 0,
                       stream, cWl, cWr, cWe, wT12);
    hipLaunchKernelGGL(transpose_kernel, dim3((EDGE_IN * HID + 255) / 256), dim3(256), 0, stream,
                       eW, eWT, EDGE_IN, HID);
    hipLaunchKernelGGL(transpose_kernel, dim3((HID * HID + 255) / 256), dim3(256), 0, stream,
                       nW1, nW1T, HID, HID);
    hipLaunchKernelGGL(transpose_kernel, dim3((HID * NODE_OUT + 255) / 256), dim3(256), 0, stream,
                       nW2, nW2T, HID, NODE_OUT);

    // 1. time MLP
    hipLaunchKernelGGL(time_mlp_kernel, dim3(N_GRAPHS), dim3(HID), 0, stream,
                       t, tW1, tb1, tW2, tb2, t_emb);
    // 2. concat
    hipLaunchKernelGGL(concat_kernel, dim3((N_NODES * 72 + 255) / 256), dim3(256), 0, stream,
                       x, conds, batch, xc);
    // 3. node encoder gemm + LN/GELU (+t_emb[batch])
    hipLaunchKernelGGL((gemm_kernel<HID, 8>), dim3(N_NODES / 8), dim3(HID), 0, stream,
                       xc, encW, encb, h, N_NODES, 72);
    hipLaunchKernelGGL(ln_gelu_kernel, dim3(N_NODES), dim3(HID), 0, stream,
                       h, encg, encbe, t_emb, batch);
    // 4. self-loop attr = segment-mean of encoded edge_attr over dst (encode fused)
    hipLaunchKernelGGL(zero_kernel, dim3(1024), dim3(256), 0, stream,
                       loop_attr, (long)N_NODES * HID);
    hipLaunchKernelGGL(zero_kernel, dim3(64), dim3(256), 0, stream, cnt, (long)N_NODES);
    hipLaunchKernelGGL((edge_enc_loop_kernel<8>), dim3(N_EDGES / 8), dim3(HID), 0, stream,
                       edge_attr, eWT, eb, eg, ebe, ei_dst, loop_attr, cnt);
    hipLaunchKernelGGL(loop_div_kernel, dim3((N_NODES * HID + 255) / 256), dim3(256), 0, stream,
                       loop_attr, cnt);

    // 5. layers
    for (int l = 0; l < NLAYERS; ++l) {
        const float* cWlT_l = wT12 + (size_t)l * 16384;
        const float* cWrT_l = wT12 + (size_t)(4 + l) * 16384;
        const float* cWeT_l = wT12 + (size_t)(8 + l) * 16384;
        const float* cbl_l = cbl + (size_t)l * HID;
        const float* cbr_l = cbr + (size_t)l * HID;
        const float* catt_l = catt + (size_t)l * HID;
        const float* cbias_l = cbias + (size_t)l * HID;

        hipLaunchKernelGGL((gemm_t_kernel<HID, 8>), dim3(N_NODES / 8), dim3(HID), 0, stream,
                           h, cWlT_l, cbl_l, xl, N_NODES);
        hipLaunchKernelGGL((gemm_t_kernel<HID, 8>), dim3(N_NODES / 8), dim3(HID), 0, stream,
                           h, cWrT_l, cbr_l, xr, N_NODES);
        hipLaunchKernelGGL(init_mx_den_kernel, dim3((N_NODES * HEADS + 255) / 256), dim3(256), 0,
                           stream, mx, den);
        hipLaunchKernelGGL((att_logit_kernel<8>), dim3(EF / 8), dim3(HID), 0, stream,
                           edge_attr, eWT, eb, eg, ebe, loop_attr,
                           cWeT_l, catt_l, xl, xr, ei_src, ei_dst, logit, mx);
        hipLaunchKernelGGL(softmax_norm_kernel,
                           dim3((int)(((long)EF * HEADS + 255) / 256)), dim3(256), 0, stream,
                           ei_dst, mx, logit, den);
        hipLaunchKernelGGL(zero_kernel, dim3(1024), dim3(256), 0, stream,
                           aggout, (long)N_NODES * HID);
        hipLaunchKernelGGL(aggregate_kernel,
                           dim3((int)(((long)EF * 32 + 255) / 256)), dim3(256), 0, stream,
                           logit, den, xl, ei_src, ei_dst, aggout);
        hipLaunchKernelGGL(residual_kernel, dim3((N_NODES * HID + 255) / 256), dim3(256), 0, stream,
                           aggout, cbias_l, h);
    }

    // 6. noise head
    hipLaunchKernelGGL((gemm_t_kernel<HID, 8>), dim3(N_NODES / 8), dim3(HID), 0, stream,
                       h, nW1T, nb1, tmp1, N_NODES);
    hipLaunchKernelGGL(ln_gelu_kernel, dim3(N_NODES), dim3(HID), 0, stream,
                       tmp1, ng, nbe, (const float*)nullptr, (const int*)nullptr);
    hipLaunchKernelGGL((gemm_t_kernel<NODE_OUT, 8>), dim3(N_NODES / 8), dim3(NODE_OUT), 0, stream,
                       tmp1, nW2T, nb2, pred_noise, N_NODES);

    // 7. pooling + props head
    hipLaunchKernelGGL(zero_kernel, dim3(4), dim3(256), 0, stream,
                       gsum, (long)N_GRAPHS * HID);
    hipLaunchKernelGGL(zero_kernel, dim3(1), dim3(64), 0, stream, gcnt, (long)N_GRAPHS);
    hipLaunchKernelGGL(pool_kernel, dim3((N_NODES + POOL_NODES - 1) / POOL_NODES), dim3(HID), 0,
                       stream, h, batch, gsum, gcnt);
    hipLaunchKernelGGL(props_kernel, dim3(N_GRAPHS), dim3(HID), 0, stream,
                       gsum, gcnt, pW1, pb1, pg, pbe, pW2, pb2, pred_props);
}

// Round 6
// 8003.182 us; speedup vs baseline: 1.6789x; 1.6060x over previous
//
#include <hip/hip_runtime.h>
#include <math.h>

#define N_NODES 30000
#define N_EDGES 480000
#define N_GRAPHS 16
#define HID 128
#define HEADS 8
#define HEAD_DIM 16
#define NODE_IN 64
#define EDGE_IN 32
#define COND 8
#define NODE_OUT 64
#define NLAYERS 4
#define EF (N_EDGES + N_NODES) /* 510000; EF%8==0, N_EDGES%8==0, N_NODES%8==0 */
#define LN_EPS 1e-5f

__device__ __forceinline__ float gelu_f(float x) {
    return 0.5f * x * (1.0f + erff(x * 0.70710678118654752440f));
}

__device__ __forceinline__ float dot4(float4 a, float4 b) {
    return a.x * b.x + a.y * b.y + a.z * b.z + a.w * b.w;
}

__device__ __forceinline__ void atomicMaxF(float* addr, float val) {
    if (val >= 0.0f) {
        atomicMax((int*)addr, __float_as_int(val));
    } else {
        atomicMin((unsigned int*)addr, __float_as_uint(val));
    }
}

// wave(64)-wide sum; all lanes end with the sum
__device__ __forceinline__ float wave_sum(float s) {
    s += __shfl_xor(s, 1);
    s += __shfl_xor(s, 2);
    s += __shfl_xor(s, 4);
    s += __shfl_xor(s, 8);
    s += __shfl_xor(s, 16);
    s += __shfl_xor(s, 32);
    return s;
}

// ---------- generic zero ----------
__global__ void zero_kernel(float* __restrict__ p, long n) {
    long i = (long)blockIdx.x * blockDim.x + threadIdx.x;
    long stride = (long)gridDim.x * blockDim.x;
    for (; i < n; i += stride) p[i] = 0.0f;
}

// ---------- transposes ----------
__global__ void transpose_kernel(const float* __restrict__ in, float* __restrict__ out,
                                 int K, int N) {
    int idx = blockIdx.x * blockDim.x + threadIdx.x;
    if (idx >= K * N) return;
    int k = idx / N, j = idx - k * N;
    out[j * K + k] = in[idx];
}

// 12 matrices of 128x128: cWl[0..3], cWr[0..3], cWe[0..3]
__global__ void batched_transpose12_kernel(const float* __restrict__ cWl,
                                           const float* __restrict__ cWr,
                                           const float* __restrict__ cWe,
                                           float* __restrict__ out) {
    int idx = blockIdx.x * blockDim.x + threadIdx.x;
    if (idx >= 12 * 16384) return;
    int m = idx >> 14;
    int r = idx & 16383;
    int k = r >> 7, j = r & 127;
    const float* base = (m < 4) ? (cWl + (size_t)m * 16384)
                      : (m < 8) ? (cWr + (size_t)(m - 4) * 16384)
                                : (cWe + (size_t)(m - 8) * 16384);
    out[(size_t)m * 16384 + j * 128 + k] = base[r];
}

// ---------- time MLP: t[16] -> t_emb[16,128] ----------
__global__ __launch_bounds__(128) void time_mlp_kernel(
    const float* __restrict__ t,
    const float* __restrict__ tW1, const float* __restrict__ tb1,
    const float* __restrict__ tW2, const float* __restrict__ tb2,
    float* __restrict__ t_emb) {
    __shared__ float hsh[HID];
    int b = blockIdx.x, j = threadIdx.x;
    float tv = t[b];
    hsh[j] = gelu_f(tv * tW1[j] + tb1[j]);
    __syncthreads();
    float acc = tb2[j];
    for (int k = 0; k < HID; ++k) acc += hsh[k] * tW2[k * HID + j];
    t_emb[b * HID + j] = acc;
}

// ---------- concat x(64) + conditions[batch](8) -> xc[N,72] ----------
__global__ void concat_kernel(const float* __restrict__ x, const float* __restrict__ cond,
                              const int* __restrict__ batch, float* __restrict__ xc) {
    int idx = blockIdx.x * blockDim.x + threadIdx.x;
    if (idx >= N_NODES * 72) return;
    int n = idx / 72, c = idx % 72;
    xc[idx] = (c < NODE_IN) ? x[n * NODE_IN + c] : cond[batch[n] * COND + (c - NODE_IN)];
}

// ---------- generic GEMM (used only for the K=72 encoder) ----------
template <int NCOL, int R>
__global__ __launch_bounds__(128) void gemm_kernel(
    const float* __restrict__ A, const float* __restrict__ B,
    const float* __restrict__ bias, float* __restrict__ C,
    int M, int K) {
    __shared__ float sh[R * HID];
    int j = threadIdx.x;
    int row0 = blockIdx.x * R;
    int total = R * K;
    for (int i = j; i < total; i += NCOL) {
        int r = i / K, k = i - r * K;
        sh[r * K + k] = A[(long)(row0 + r) * K + k];
    }
    __syncthreads();
    float acc[R];
    float bv = bias ? bias[j] : 0.0f;
#pragma unroll
    for (int r = 0; r < R; ++r) acc[r] = bv;
    for (int k = 0; k < K; ++k) {
        float w = B[k * NCOL + j];
#pragma unroll
        for (int r = 0; r < R; ++r) acc[r] += sh[r * K + k] * w;
    }
#pragma unroll
    for (int r = 0; r < R; ++r) C[(long)(row0 + r) * NCOL + j] = acc[r];
}

// ---------- GEMM with transposed B, K=128 (M % R == 0 assumed) ----------
template <int NCOL, int R>
__global__ __launch_bounds__(128, 4) void gemm_t_kernel(
    const float* __restrict__ A, const float* __restrict__ BT,
    const float* __restrict__ bias, float* __restrict__ C, int M) {
    __shared__ __align__(16) float sh[R * HID];
    int j = threadIdx.x;
    int row0 = blockIdx.x * R;
    const float4* A4 = (const float4*)A;
    float4* sh4 = (float4*)sh;
    for (int i = j; i < R * 32; i += NCOL) {
        sh4[i] = A4[(long)row0 * 32 + i];
    }
    __syncthreads();
    float acc[R];
#pragma unroll
    for (int r = 0; r < R; ++r) acc[r] = 0.0f;
    const float4* wT = (const float4*)(BT + (size_t)j * HID);
#pragma unroll 1
    for (int kc = 0; kc < 16; ++kc) {
        float4 w0 = wT[kc * 2 + 0], w1 = wT[kc * 2 + 1];
#pragma unroll
        for (int r = 0; r < R; ++r) {
            const float4* s4 = (const float4*)&sh[r * HID + kc * 8];
            acc[r] += dot4(s4[0], w0) + dot4(s4[1], w1);
        }
    }
    float bv = bias ? bias[j] : 0.0f;
#pragma unroll
    for (int r = 0; r < R; ++r) {
        C[(long)(row0 + r) * NCOL + j] = acc[r] + bv;
    }
}

// ---------- in-place LayerNorm + GELU (+ optional t_emb[batch[row]]) ----------
__global__ __launch_bounds__(128) void ln_gelu_kernel(
    float* __restrict__ X, const float* __restrict__ g,
    const float* __restrict__ bta,
    const float* __restrict__ t_emb, const int* __restrict__ batch) {
    int row = blockIdx.x, j = threadIdx.x;
    __shared__ float wred[2], wred2[2];
    int wave = j >> 6, lane = j & 63;
    float v = X[(long)row * HID + j];
    float s = wave_sum(v);
    if (lane == 0) wred[wave] = s;
    __syncthreads();
    float mean = (wred[0] + wred[1]) * (1.0f / HID);
    float d = v - mean;
    float s2 = wave_sum(d * d);
    if (lane == 0) wred2[wave] = s2;
    __syncthreads();
    float var = (wred2[0] + wred2[1]) * (1.0f / HID);
    float y = gelu_f(d * rsqrtf(var + LN_EPS) * g[j] + bta[j]);
    if (t_emb) y += t_emb[batch[row] * HID + j];
    X[(long)row * HID + j] = y;
}

// ---------- fused: edge-encode + segment-sum into loop_sum/cnt ----------
// N_EDGES % R == 0: no tail handling anywhere.
template <int R>
__global__ __launch_bounds__(128, 4) void edge_enc_loop_kernel(
    const float* __restrict__ edge_attr,
    const float* __restrict__ eWT, /* [128][32] */
    const float* __restrict__ eb,
    const float* __restrict__ eg, const float* __restrict__ ebe,
    const int* __restrict__ ei_dst,
    float* __restrict__ loop_sum, float* __restrict__ cnt) {
    __shared__ __align__(16) float sattr[R * EDGE_IN];
    __shared__ float wred[2][R], wred2[2][R];
    __shared__ int sdst[R];
    int j = threadIdx.x;
    int wave = j >> 6, lane = j & 63;
    long e0 = (long)blockIdx.x * R;
    if (j < R * 8) ((float4*)sattr)[j] = ((const float4*)edge_attr)[e0 * 8 + j];
    if (j < R) sdst[j] = ei_dst[e0 + j];
    __syncthreads();
    float val[R];
    float ebj = eb[j];
#pragma unroll
    for (int r = 0; r < R; ++r) val[r] = ebj;
    const float4* ewr = (const float4*)(eWT + (size_t)j * EDGE_IN);
#pragma unroll 1
    for (int q = 0; q < 8; ++q) {
        float4 wq = ewr[q];
#pragma unroll
        for (int r = 0; r < R; ++r) {
            float4 a = *(const float4*)&sattr[r * EDGE_IN + q * 4];
            val[r] += dot4(a, wq);
        }
    }
#pragma unroll
    for (int r = 0; r < R; ++r) {
        float s = wave_sum(val[r]);
        if (lane == 0) wred[wave][r] = s;
    }
    __syncthreads();
#pragma unroll
    for (int r = 0; r < R; ++r) {
        float mean = (wred[0][r] + wred[1][r]) * (1.0f / HID);
        float d = val[r] - mean;
        val[r] = d;
        float s = wave_sum(d * d);
        if (lane == 0) wred2[wave][r] = s;
    }
    __syncthreads();
    float egj = eg[j], ebej = ebe[j];
#pragma unroll 2
    for (int r = 0; r < R; ++r) {
        float var = (wred2[0][r] + wred2[1][r]) * (1.0f / HID);
        float y = gelu_f(val[r] * rsqrtf(var + LN_EPS) * egj + ebej);
        int d = sdst[r];
        atomicAdd(&loop_sum[(long)d * HID + j], y);
        if (j == 0) atomicAdd(&cnt[d], 1.0f);
    }
}

__global__ void loop_div_kernel(float* __restrict__ loop_attr, const float* __restrict__ cnt) {
    int idx = blockIdx.x * blockDim.x + threadIdx.x;
    if (idx >= N_NODES * HID) return;
    int n = idx >> 7;
    loop_attr[idx] = loop_attr[idx] / fmaxf(cnt[n], 1.0f);
}

// ---------- init mx=-inf, den=0 ----------
__global__ void init_mx_den_kernel(float* __restrict__ mx, float* __restrict__ den) {
    int idx = blockIdx.x * blockDim.x + threadIdx.x;
    if (idx >= N_NODES * HEADS) return;
    mx[idx] = -INFINITY;
    den[idx] = 0.0f;
}

// ---------- fused: edge-encode recompute + em-GEMM + leakyrelu + logit + atomicMax ----------
// EF % R == 0 and N_EDGES % R == 0: blocks are full and never straddle the boundary.
template <int R>
__global__ __launch_bounds__(128, 4) void att_logit_kernel(
    const float* __restrict__ edge_attr,
    const float* __restrict__ eWT, /* [128][32] */
    const float* __restrict__ eb,
    const float* __restrict__ eg, const float* __restrict__ ebe,
    const float* __restrict__ loop_attr,
    const float* __restrict__ cWeT_l, /* [128][128] (transposed) */
    const float* __restrict__ catt_l, /* [128] */
    const float* __restrict__ xl, const float* __restrict__ xr,
    const int* __restrict__ ei_src, const int* __restrict__ ei_dst,
    float* __restrict__ logit, float* __restrict__ mx) {
    __shared__ __align__(16) float sh[R * HID];
    __shared__ __align__(16) float sattr[R * EDGE_IN];
    __shared__ float wred[2][R], wred2[2][R];
    __shared__ int ssrc[R], sdst[R];
    int j = threadIdx.x;
    int wave = j >> 6, lane = j & 63;
    long e0 = (long)blockIdx.x * R;
    bool real_block = (e0 < N_EDGES);
    if (real_block && j < R * 8) {
        ((float4*)sattr)[j] = ((const float4*)edge_attr)[e0 * 8 + j];
    }
    if (j < R) {
        long e = e0 + j;
        if (e < N_EDGES) { ssrc[j] = ei_src[e]; sdst[j] = ei_dst[e]; }
        else             { ssrc[j] = sdst[j] = (int)(e - N_EDGES); }
    }
    __syncthreads();
    if (real_block) {
        // edge-encode: val = edge_attr @ eW + eb   (q-outer: one weight float4 live)
        float val[R];
        float ebj = eb[j];
#pragma unroll
        for (int r = 0; r < R; ++r) val[r] = ebj;
        const float4* ewr = (const float4*)(eWT + (size_t)j * EDGE_IN);
#pragma unroll 1
        for (int q = 0; q < 8; ++q) {
            float4 wq = ewr[q];
#pragma unroll
            for (int r = 0; r < R; ++r) {
                float4 a = *(const float4*)&sattr[r * EDGE_IN + q * 4];
                val[r] += dot4(a, wq);
            }
        }
        // LN across the 128 columns
#pragma unroll
        for (int r = 0; r < R; ++r) {
            float s = wave_sum(val[r]);
            if (lane == 0) wred[wave][r] = s;
        }
        __syncthreads();
#pragma unroll
        for (int r = 0; r < R; ++r) {
            float mean = (wred[0][r] + wred[1][r]) * (1.0f / HID);
            float d = val[r] - mean;
            val[r] = d;
            float s = wave_sum(d * d);
            if (lane == 0) wred2[wave][r] = s;
        }
        __syncthreads();
        float egj = eg[j], ebej = ebe[j];
#pragma unroll
        for (int r = 0; r < R; ++r) {
            float var = (wred2[0][r] + wred2[1][r]) * (1.0f / HID);
            sh[r * HID + j] = gelu_f(val[r] * rsqrtf(var + LN_EPS) * egj + ebej);
        }
    } else {
        // self-loop rows: loop_attr is already the final ea row
#pragma unroll
        for (int r = 0; r < R; ++r) {
            sh[r * HID + j] = loop_attr[(long)(e0 + r - N_EDGES) * HID + j];
        }
    }
    __syncthreads();
    // em GEMM: acc[r] = dot(sh_row_r, cWeT_row_j)
    float acc[R];
#pragma unroll
    for (int r = 0; r < R; ++r) acc[r] = 0.0f;
    const float4* wT = (const float4*)(cWeT_l + (size_t)j * HID);
#pragma unroll 1
    for (int kc = 0; kc < 16; ++kc) {
        float4 w0 = wT[kc * 2 + 0], w1 = wT[kc * 2 + 1];
#pragma unroll
        for (int r = 0; r < R; ++r) {
            const float4* s4 = (const float4*)&sh[r * HID + kc * 8];
            acc[r] += dot4(s4[0], w0) + dot4(s4[1], w1);
        }
    }
    float cj = catt_l[j];
    int head = j >> 4;
#pragma unroll 2
    for (int r = 0; r < R; ++r) {
        long e = e0 + r;
        int s = ssrc[r], d = sdst[r];
        float m = xl[(long)s * HID + j] + xr[(long)d * HID + j] + acc[r];
        m = (m > 0.0f) ? m : 0.2f * m;
        float p = m * cj;
        p += __shfl_down(p, 8, 16);
        p += __shfl_down(p, 4, 16);
        p += __shfl_down(p, 2, 16);
        p += __shfl_down(p, 1, 16);
        if ((j & 15) == 0) {
            logit[e * HEADS + head] = p;
            atomicMaxF(&mx[(long)d * HEADS + head], p);
        }
    }
}

// ---------- exp(logit-mx), accumulate denominator ----------
__global__ void softmax_norm_kernel(const int* __restrict__ ei_dst, const float* __restrict__ mx,
                                    float* __restrict__ logit, float* __restrict__ den) {
    long idx = (long)blockIdx.x * blockDim.x + threadIdx.x;
    if (idx >= (long)EF * HEADS) return;
    long e = idx >> 3;
    int hh = (int)(idx & 7);
    int d = (e < N_EDGES) ? ei_dst[e] : (int)(e - N_EDGES);
    float ex = expf(logit[idx] - mx[(long)d * HEADS + hh]);
    logit[idx] = ex;
    atomicAdd(&den[(long)d * HEADS + hh], ex);
}

// ---------- alpha-weighted aggregation (float4: 4 cols/thread) ----------
__global__ void aggregate_kernel(const float* __restrict__ logit, const float* __restrict__ den,
                                 const float* __restrict__ xl,
                                 const int* __restrict__ ei_src, const int* __restrict__ ei_dst,
                                 float* __restrict__ aggout) {
    long idx = (long)blockIdx.x * blockDim.x + threadIdx.x;
    if (idx >= (long)EF * 32) return;
    long e = idx >> 5;
    int q = (int)(idx & 31);  // 4-col group
    int j0 = q << 2;
    int head = q >> 2;
    int s, d;
    if (e < N_EDGES) { s = ei_src[e]; d = ei_dst[e]; }
    else             { s = d = (int)(e - N_EDGES); }
    float alpha = logit[e * HEADS + head] / (den[(long)d * HEADS + head] + 1e-16f);
    float4 xv = *(const float4*)&xl[(long)s * HID + j0];
    float* dst = &aggout[(long)d * HID + j0];
    atomicAdd(dst + 0, alpha * xv.x);
    atomicAdd(dst + 1, alpha * xv.y);
    atomicAdd(dst + 2, alpha * xv.z);
    atomicAdd(dst + 3, alpha * xv.w);
}

// ---------- h = gelu(aggout + cbias) + h ----------
__global__ void residual_kernel(const float* __restrict__ aggout, const float* __restrict__ cbias_l,
                                float* __restrict__ h) {
    int idx = blockIdx.x * blockDim.x + threadIdx.x;
    if (idx >= N_NODES * HID) return;
    int j = idx & 127;
    h[idx] = gelu_f(aggout[idx] + cbias_l[j]) + h[idx];
}

// ---------- pooling ----------
#define POOL_NODES 64
__global__ __launch_bounds__(128) void pool_kernel(
    const float* __restrict__ h, const int* __restrict__ batch,
    float* __restrict__ gsum, float* __restrict__ gcnt) {
    __shared__ float acc[N_GRAPHS][HID];
    __shared__ float cnt_sh[N_GRAPHS];
    int j = threadIdx.x;
    for (int g = 0; g < N_GRAPHS; ++g) acc[g][j] = 0.0f;
    if (j < N_GRAPHS) cnt_sh[j] = 0.0f;
    __syncthreads();
    int n0 = blockIdx.x * POOL_NODES;
    for (int i = 0; i < POOL_NODES; ++i) {
        int n = n0 + i;
        if (n >= N_NODES) break;
        int g = batch[n];
        acc[g][j] += h[(long)n * HID + j];
        if (j == 0) cnt_sh[g] += 1.0f;
    }
    __syncthreads();
    for (int g = 0; g < N_GRAPHS; ++g) atomicAdd(&gsum[g * HID + j], acc[g][j]);
    if (j < N_GRAPHS) atomicAdd(&gcnt[j], cnt_sh[j]);
}

// ---------- props head ----------
__global__ __launch_bounds__(128) void props_kernel(
    const float* __restrict__ gsum, const float* __restrict__ gcnt,
    const float* __restrict__ pW1, const float* __restrict__ pb1,
    const float* __restrict__ pg, const float* __restrict__ pbe,
    const float* __restrict__ pW2, const float* __restrict__ pb2,
    float* __restrict__ out_props) {
    int g = blockIdx.x, j = threadIdx.x;
    __shared__ float feat[HID], red[HID], t2[HID];
    float c = fmaxf(gcnt[g], 1.0f);
    feat[j] = gsum[g * HID + j] / c;
    __syncthreads();
    float acc = pb1[j];
    for (int k = 0; k < HID; ++k) acc += feat[k] * pW1[k * HID + j];
    red[j] = acc;
    __syncthreads();
    for (int s = 64; s > 0; s >>= 1) { if (j < s) red[j] += red[j + s]; __syncthreads(); }
    float mean = red[0] * (1.0f / HID);
    __syncthreads();
    float dd = acc - mean;
    red[j] = dd * dd;
    __syncthreads();
    for (int s = 64; s > 0; s >>= 1) { if (j < s) red[j] += red[j + s]; __syncthreads(); }
    float var = red[0] * (1.0f / HID);
    t2[j] = gelu_f(dd * rsqrtf(var + LN_EPS) * pg[j] + pbe[j]);
    __syncthreads();
    if (j < COND) {
        float a = pb2[j];
        for (int k = 0; k < HID; ++k) a += t2[k] * pW2[k * COND + j];
        out_props[g * COND + j] = a;
    }
}

extern "C" void kernel_launch(void* const* d_in, const int* in_sizes, int n_in,
                              void* d_out, int out_size, void* d_ws, size_t ws_size,
                              hipStream_t stream) {
    const float* x        = (const float*)d_in[0];
    const float* edge_attr= (const float*)d_in[1];
    const float* t        = (const float*)d_in[2];
    const float* conds    = (const float*)d_in[3];
    const float* tW1      = (const float*)d_in[4];
    const float* tb1      = (const float*)d_in[5];
    const float* tW2      = (const float*)d_in[6];
    const float* tb2      = (const float*)d_in[7];
    const float* encW     = (const float*)d_in[8];
    const float* encb     = (const float*)d_in[9];
    const float* encg     = (const float*)d_in[10];
    const float* encbe    = (const float*)d_in[11];
    const float* eW       = (const float*)d_in[12];
    const float* eb       = (const float*)d_in[13];
    const float* eg       = (const float*)d_in[14];
    const float* ebe      = (const float*)d_in[15];
    const float* cWl      = (const float*)d_in[16];
    const float* cbl      = (const float*)d_in[17];
    const float* cWr      = (const float*)d_in[18];
    const float* cbr      = (const float*)d_in[19];
    const float* cWe      = (const float*)d_in[20];
    const float* catt     = (const float*)d_in[21];
    const float* cbias    = (const float*)d_in[22];
    const float* nW1      = (const float*)d_in[23];
    const float* nb1      = (const float*)d_in[24];
    const float* ng       = (const float*)d_in[25];
    const float* nbe      = (const float*)d_in[26];
    const float* nW2      = (const float*)d_in[27];
    const float* nb2      = (const float*)d_in[28];
    const float* pW1      = (const float*)d_in[29];
    const float* pb1      = (const float*)d_in[30];
    const float* pg       = (const float*)d_in[31];
    const float* pbe      = (const float*)d_in[32];
    const float* pW2      = (const float*)d_in[33];
    const float* pb2      = (const float*)d_in[34];
    const int* edge_index = (const int*)d_in[35];
    const int* batch      = (const int*)d_in[36];
    const int* ei_src = edge_index;
    const int* ei_dst = edge_index + N_EDGES;

    // workspace layout (~95 MB of f32)
    float* ws = (float*)d_ws;
    size_t off = 0;
    auto alloc = [&](size_t n) { float* p = ws + off; off += n; return p; };
    float* t_emb     = alloc((size_t)N_GRAPHS * HID);
    float* h         = alloc((size_t)N_NODES * HID);
    float* loop_attr = alloc((size_t)N_NODES * HID);
    float* cnt       = alloc((size_t)N_NODES);
    float* xl        = alloc((size_t)N_NODES * HID);
    float* xr        = alloc((size_t)N_NODES * HID);
    float* logit     = alloc((size_t)EF * HEADS);      // 4.08M floats
    float* mx        = alloc((size_t)N_NODES * HEADS);
    float* den       = alloc((size_t)N_NODES * HEADS);
    float* aggout    = alloc((size_t)N_NODES * HID);
    float* gsum      = alloc((size_t)N_GRAPHS * HID);
    float* gcnt      = alloc((size_t)N_GRAPHS);
    float* wT12      = alloc((size_t)12 * 16384);      // cWlT[4] | cWrT[4] | cWeT[4]
    float* eWT       = alloc((size_t)HID * EDGE_IN);
    float* nW1T      = alloc((size_t)HID * HID);
    float* nW2T      = alloc((size_t)NODE_OUT * HID);
    // aliases (disjoint lifetimes):
    float* xc   = logit;  // [N,72] pre-layer only; logit is bigger
    float* tmp1 = xl;     // post-layer only
    (void)ws_size; (void)in_sizes; (void)n_in; (void)out_size;

    float* pred_noise = (float*)d_out;                              // [N,64]
    float* pred_props = (float*)d_out + (size_t)N_NODES * NODE_OUT; // [16,8]

    // 0. weight transposes
    hipLaunchKernelGGL(batched_transpose12_kernel, dim3((12 * 16384 + 255) / 256), dim3(256), 0,
                       stream, cWl, cWr, cWe, wT12);
    hipLaunchKernelGGL(transpose_kernel, dim3((EDGE_IN * HID + 255) / 256), dim3(256), 0, stream,
                       eW, eWT, EDGE_IN, HID);
    hipLaunchKernelGGL(transpose_kernel, dim3((HID * HID + 255) / 256), dim3(256), 0, stream,
                       nW1, nW1T, HID, HID);
    hipLaunchKernelGGL(transpose_kernel, dim3((HID * NODE_OUT + 255) / 256), dim3(256), 0, stream,
                       nW2, nW2T, HID, NODE_OUT);

    // 1. time MLP
    hipLaunchKernelGGL(time_mlp_kernel, dim3(N_GRAPHS), dim3(HID), 0, stream,
                       t, tW1, tb1, tW2, tb2, t_emb);
    // 2. concat
    hipLaunchKernelGGL(concat_kernel, dim3((N_NODES * 72 + 255) / 256), dim3(256), 0, stream,
                       x, conds, batch, xc);
    // 3. node encoder gemm + LN/GELU (+t_emb[batch])
    hipLaunchKernelGGL((gemm_kernel<HID, 8>), dim3(N_NODES / 8), dim3(HID), 0, stream,
                       xc, encW, encb, h, N_NODES, 72);
    hipLaunchKernelGGL(ln_gelu_kernel, dim3(N_NODES), dim3(HID), 0, stream,
                       h, encg, encbe, t_emb, batch);
    // 4. self-loop attr = segment-mean of encoded edge_attr over dst (encode fused)
    hipLaunchKernelGGL(zero_kernel, dim3(1024), dim3(256), 0, stream,
                       loop_attr, (long)N_NODES * HID);
    hipLaunchKernelGGL(zero_kernel, dim3(64), dim3(256), 0, stream, cnt, (long)N_NODES);
    hipLaunchKernelGGL((edge_enc_loop_kernel<8>), dim3(N_EDGES / 8), dim3(HID), 0, stream,
                       edge_attr, eWT, eb, eg, ebe, ei_dst, loop_attr, cnt);
    hipLaunchKernelGGL(loop_div_kernel, dim3((N_NODES * HID + 255) / 256), dim3(256), 0, stream,
                       loop_attr, cnt);

    // 5. layers
    for (int l = 0; l < NLAYERS; ++l) {
        const float* cWlT_l = wT12 + (size_t)l * 16384;
        const float* cWrT_l = wT12 + (size_t)(4 + l) * 16384;
        const float* cWeT_l = wT12 + (size_t)(8 + l) * 16384;
        const float* cbl_l = cbl + (size_t)l * HID;
        const float* cbr_l = cbr + (size_t)l * HID;
        const float* catt_l = catt + (size_t)l * HID;
        const float* cbias_l = cbias + (size_t)l * HID;

        hipLaunchKernelGGL((gemm_t_kernel<HID, 8>), dim3(N_NODES / 8), dim3(HID), 0, stream,
                           h, cWlT_l, cbl_l, xl, N_NODES);
        hipLaunchKernelGGL((gemm_t_kernel<HID, 8>), dim3(N_NODES / 8), dim3(HID), 0, stream,
                           h, cWrT_l, cbr_l, xr, N_NODES);
        hipLaunchKernelGGL(init_mx_den_kernel, dim3((N_NODES * HEADS + 255) / 256), dim3(256), 0,
                           stream, mx, den);
        hipLaunchKernelGGL((att_logit_kernel<8>), dim3(EF / 8), dim3(HID), 0, stream,
                           edge_attr, eWT, eb, eg, ebe, loop_attr,
                           cWeT_l, catt_l, xl, xr, ei_src, ei_dst, logit, mx);
        hipLaunchKernelGGL(softmax_norm_kernel,
                           dim3((int)(((long)EF * HEADS + 255) / 256)), dim3(256), 0, stream,
                           ei_dst, mx, logit, den);
        hipLaunchKernelGGL(zero_kernel, dim3(1024), dim3(256), 0, stream,
                           aggout, (long)N_NODES * HID);
        hipLaunchKernelGGL(aggregate_kernel,
                           dim3((int)(((long)EF * 32 + 255) / 256)), dim3(256), 0, stream,
                           logit, den, xl, ei_src, ei_dst, aggout);
        hipLaunchKernelGGL(residual_kernel, dim3((N_NODES * HID + 255) / 256), dim3(256), 0, stream,
                           aggout, cbias_l, h);
    }

    // 6. noise head
    hipLaunchKernelGGL((gemm_t_kernel<HID, 8>), dim3(N_NODES / 8), dim3(HID), 0, stream,
                       h, nW1T, nb1, tmp1, N_NODES);
    hipLaunchKernelGGL(ln_gelu_kernel, dim3(N_NODES), dim3(HID), 0, stream,
                       tmp1, ng, nbe, (const float*)nullptr, (const int*)nullptr);
    hipLaunchKernelGGL((gemm_t_kernel<NODE_OUT, 8>), dim3(N_NODES / 8), dim3(NODE_OUT), 0, stream,
                       tmp1, nW2T, nb2, pred_noise, N_NODES);

    // 7. pooling + props head
    hipLaunchKernelGGL(zero_kernel, dim3(4), dim3(256), 0, stream,
                       gsum, (long)N_GRAPHS * HID);
    hipLaunchKernelGGL(zero_kernel, dim3(1), dim3(64), 0, stream, gcnt, (long)N_GRAPHS);
    hipLaunchKernelGGL(pool_kernel, dim3((N_NODES + POOL_NODES - 1) / POOL_NODES), dim3(HID), 0,
                       stream, h, batch, gsum, gcnt);
    hipLaunchKernelGGL(props_kernel, dim3(N_GRAPHS), dim3(HID), 0, stream,
                       gsum, gcnt, pW1, pb1, pg, pbe, pW2, pb2, pred_props);
}

// Round 7
// 6187.932 us; speedup vs baseline: 2.1715x; 1.2934x over previous
//
#include <hip/hip_runtime.h>
#include <math.h>

#define N_NODES 30000
#define N_EDGES 480000
#define N_GRAPHS 16
#define HID 128
#define HEADS 8
#define HEAD_DIM 16
#define NODE_IN 64
#define EDGE_IN 32
#define COND 8
#define NODE_OUT 64
#define NLAYERS 4
#define EF (N_EDGES + N_NODES) /* 510000; EF%8==0, N_EDGES%8==0, N_NODES%8==0 */
#define LN_EPS 1e-5f

typedef __bf16 bf16x8_t __attribute__((ext_vector_type(8)));
typedef float f32x4_t __attribute__((ext_vector_type(4)));

#define ATS_LD 136  /* 128 + 8 bf16 pad: row stride 272 B breaks bank aliasing */

__device__ __forceinline__ float gelu_f(float x) {
    return 0.5f * x * (1.0f + erff(x * 0.70710678118654752440f));
}

__device__ __forceinline__ float dot4(float4 a, float4 b) {
    return a.x * b.x + a.y * b.y + a.z * b.z + a.w * b.w;
}

__device__ __forceinline__ void atomicMaxF(float* addr, float val) {
    if (val >= 0.0f) {
        atomicMax((int*)addr, __float_as_int(val));
    } else {
        atomicMin((unsigned int*)addr, __float_as_uint(val));
    }
}

// wave(64)-wide sum; all lanes end with the sum
__device__ __forceinline__ float wave_sum(float s) {
    s += __shfl_xor(s, 1);
    s += __shfl_xor(s, 2);
    s += __shfl_xor(s, 4);
    s += __shfl_xor(s, 8);
    s += __shfl_xor(s, 16);
    s += __shfl_xor(s, 32);
    return s;
}

// ---------- generic zero ----------
__global__ void zero_kernel(float* __restrict__ p, long n) {
    long i = (long)blockIdx.x * blockDim.x + threadIdx.x;
    long stride = (long)gridDim.x * blockDim.x;
    for (; i < n; i += stride) p[i] = 0.0f;
}

// ---------- transposes ----------
__global__ void transpose_kernel(const float* __restrict__ in, float* __restrict__ out,
                                 int K, int N) {
    int idx = blockIdx.x * blockDim.x + threadIdx.x;
    if (idx >= K * N) return;
    int k = idx / N, j = idx - k * N;
    out[j * K + k] = in[idx];
}

// 12 matrices of 128x128: cWl[0..3], cWr[0..3], cWe[0..3]
__global__ void batched_transpose12_kernel(const float* __restrict__ cWl,
                                           const float* __restrict__ cWr,
                                           const float* __restrict__ cWe,
                                           float* __restrict__ out) {
    int idx = blockIdx.x * blockDim.x + threadIdx.x;
    if (idx >= 12 * 16384) return;
    int m = idx >> 14;
    int r = idx & 16383;
    int k = r >> 7, j = r & 127;
    const float* base = (m < 4) ? (cWl + (size_t)m * 16384)
                      : (m < 8) ? (cWr + (size_t)(m - 4) * 16384)
                                : (cWe + (size_t)(m - 8) * 16384);
    out[(size_t)m * 16384 + j * 128 + k] = base[r];
}

// ---------- pack cWe (4 layers) into bf16 B-fragment layout ----------
// out[l][(g*128 + n)*8 + jj] = bf16(cWe[l][(8g+jj)*128 + n]),  g=k-group (0..15)
__global__ void pack_cwe_bf16_kernel(const float* __restrict__ cWe, __bf16* __restrict__ out) {
    int idx = blockIdx.x * blockDim.x + threadIdx.x;
    if (idx >= 4 * 16384) return;
    int l = idx >> 14;
    int r = idx & 16383;
    int g = r >> 10;
    int q = r & 1023;
    int n = q >> 3, jj = q & 7;
    out[(size_t)l * 16384 + (size_t)(g * 128 + n) * 8 + jj] =
        (__bf16)cWe[(size_t)l * 16384 + (size_t)(8 * g + jj) * 128 + n];
}

// ---------- time MLP: t[16] -> t_emb[16,128] ----------
__global__ __launch_bounds__(128) void time_mlp_kernel(
    const float* __restrict__ t,
    const float* __restrict__ tW1, const float* __restrict__ tb1,
    const float* __restrict__ tW2, const float* __restrict__ tb2,
    float* __restrict__ t_emb) {
    __shared__ float hsh[HID];
    int b = blockIdx.x, j = threadIdx.x;
    float tv = t[b];
    hsh[j] = gelu_f(tv * tW1[j] + tb1[j]);
    __syncthreads();
    float acc = tb2[j];
    for (int k = 0; k < HID; ++k) acc += hsh[k] * tW2[k * HID + j];
    t_emb[b * HID + j] = acc;
}

// ---------- concat x(64) + conditions[batch](8) -> xc[N,72] ----------
__global__ void concat_kernel(const float* __restrict__ x, const float* __restrict__ cond,
                              const int* __restrict__ batch, float* __restrict__ xc) {
    int idx = blockIdx.x * blockDim.x + threadIdx.x;
    if (idx >= N_NODES * 72) return;
    int n = idx / 72, c = idx % 72;
    xc[idx] = (c < NODE_IN) ? x[n * NODE_IN + c] : cond[batch[n] * COND + (c - NODE_IN)];
}

// ---------- generic GEMM (used only for the K=72 encoder) ----------
template <int NCOL, int R>
__global__ __launch_bounds__(128) void gemm_kernel(
    const float* __restrict__ A, const float* __restrict__ B,
    const float* __restrict__ bias, float* __restrict__ C,
    int M, int K) {
    __shared__ float sh[R * HID];
    int j = threadIdx.x;
    int row0 = blockIdx.x * R;
    int total = R * K;
    for (int i = j; i < total; i += NCOL) {
        int r = i / K, k = i - r * K;
        sh[r * K + k] = A[(long)(row0 + r) * K + k];
    }
    __syncthreads();
    float acc[R];
    float bv = bias ? bias[j] : 0.0f;
#pragma unroll
    for (int r = 0; r < R; ++r) acc[r] = bv;
    for (int k = 0; k < K; ++k) {
        float w = B[k * NCOL + j];
#pragma unroll
        for (int r = 0; r < R; ++r) acc[r] += sh[r * K + k] * w;
    }
#pragma unroll
    for (int r = 0; r < R; ++r) C[(long)(row0 + r) * NCOL + j] = acc[r];
}

// ---------- GEMM with transposed B, K=128 (M % R == 0 assumed) ----------
template <int NCOL, int R>
__global__ __launch_bounds__(128, 4) void gemm_t_kernel(
    const float* __restrict__ A, const float* __restrict__ BT,
    const float* __restrict__ bias, float* __restrict__ C, int M) {
    __shared__ __align__(16) float sh[R * HID];
    int j = threadIdx.x;
    int row0 = blockIdx.x * R;
    const float4* A4 = (const float4*)A;
    float4* sh4 = (float4*)sh;
    for (int i = j; i < R * 32; i += NCOL) {
        sh4[i] = A4[(long)row0 * 32 + i];
    }
    __syncthreads();
    float acc[R];
#pragma unroll
    for (int r = 0; r < R; ++r) acc[r] = 0.0f;
    const float4* wT = (const float4*)(BT + (size_t)j * HID);
#pragma unroll 1
    for (int kc = 0; kc < 16; ++kc) {
        float4 w0 = wT[kc * 2 + 0], w1 = wT[kc * 2 + 1];
#pragma unroll
        for (int r = 0; r < R; ++r) {
            const float4* s4 = (const float4*)&sh[r * HID + kc * 8];
            acc[r] += dot4(s4[0], w0) + dot4(s4[1], w1);
        }
    }
    float bv = bias ? bias[j] : 0.0f;
#pragma unroll
    for (int r = 0; r < R; ++r) {
        C[(long)(row0 + r) * NCOL + j] = acc[r] + bv;
    }
}

// ---------- in-place LayerNorm + GELU (+ optional t_emb[batch[row]]) ----------
__global__ __launch_bounds__(128) void ln_gelu_kernel(
    float* __restrict__ X, const float* __restrict__ g,
    const float* __restrict__ bta,
    const float* __restrict__ t_emb, const int* __restrict__ batch) {
    int row = blockIdx.x, j = threadIdx.x;
    __shared__ float wred[2], wred2[2];
    int wave = j >> 6, lane = j & 63;
    float v = X[(long)row * HID + j];
    float s = wave_sum(v);
    if (lane == 0) wred[wave] = s;
    __syncthreads();
    float mean = (wred[0] + wred[1]) * (1.0f / HID);
    float d = v - mean;
    float s2 = wave_sum(d * d);
    if (lane == 0) wred2[wave] = s2;
    __syncthreads();
    float var = (wred2[0] + wred2[1]) * (1.0f / HID);
    float y = gelu_f(d * rsqrtf(var + LN_EPS) * g[j] + bta[j]);
    if (t_emb) y += t_emb[batch[row] * HID + j];
    X[(long)row * HID + j] = y;
}

// ---------- fused: edge-encode + segment-sum into loop_sum/cnt ----------
// N_EDGES % R == 0: no tail handling anywhere.
template <int R>
__global__ __launch_bounds__(128, 4) void edge_enc_loop_kernel(
    const float* __restrict__ edge_attr,
    const float* __restrict__ eWT, /* [128][32] */
    const float* __restrict__ eb,
    const float* __restrict__ eg, const float* __restrict__ ebe,
    const int* __restrict__ ei_dst,
    float* __restrict__ loop_sum, float* __restrict__ cnt) {
    __shared__ __align__(16) float sattr[R * EDGE_IN];
    __shared__ float wred[2][R], wred2[2][R];
    __shared__ int sdst[R];
    int j = threadIdx.x;
    int wave = j >> 6, lane = j & 63;
    long e0 = (long)blockIdx.x * R;
    if (j < R * 8) ((float4*)sattr)[j] = ((const float4*)edge_attr)[e0 * 8 + j];
    if (j < R) sdst[j] = ei_dst[e0 + j];
    __syncthreads();
    float val[R];
    float ebj = eb[j];
#pragma unroll
    for (int r = 0; r < R; ++r) val[r] = ebj;
    const float4* ewr = (const float4*)(eWT + (size_t)j * EDGE_IN);
#pragma unroll 1
    for (int q = 0; q < 8; ++q) {
        float4 wq = ewr[q];
#pragma unroll
        for (int r = 0; r < R; ++r) {
            float4 a = *(const float4*)&sattr[r * EDGE_IN + q * 4];
            val[r] += dot4(a, wq);
        }
    }
#pragma unroll
    for (int r = 0; r < R; ++r) {
        float s = wave_sum(val[r]);
        if (lane == 0) wred[wave][r] = s;
    }
    __syncthreads();
#pragma unroll
    for (int r = 0; r < R; ++r) {
        float mean = (wred[0][r] + wred[1][r]) * (1.0f / HID);
        float d = val[r] - mean;
        val[r] = d;
        float s = wave_sum(d * d);
        if (lane == 0) wred2[wave][r] = s;
    }
    __syncthreads();
    float egj = eg[j], ebej = ebe[j];
#pragma unroll 2
    for (int r = 0; r < R; ++r) {
        float var = (wred2[0][r] + wred2[1][r]) * (1.0f / HID);
        float y = gelu_f(val[r] * rsqrtf(var + LN_EPS) * egj + ebej);
        int d = sdst[r];
        atomicAdd(&loop_sum[(long)d * HID + j], y);
        if (j == 0) atomicAdd(&cnt[d], 1.0f);
    }
}

__global__ void loop_div_kernel(float* __restrict__ loop_attr, const float* __restrict__ cnt) {
    int idx = blockIdx.x * blockDim.x + threadIdx.x;
    if (idx >= N_NODES * HID) return;
    int n = idx >> 7;
    loop_attr[idx] = loop_attr[idx] / fmaxf(cnt[n], 1.0f);
}

// ---------- init mx=-inf, den=0 ----------
__global__ void init_mx_den_kernel(float* __restrict__ mx, float* __restrict__ den) {
    int idx = blockIdx.x * blockDim.x + threadIdx.x;
    if (idx >= N_NODES * HEADS) return;
    mx[idx] = -INFINITY;
    den[idx] = 0.0f;
}

// ---------- fused: edge-encode recompute + MFMA em-GEMM + leakyrelu + logit + atomicMax ----
// EF % R == 0 and N_EDGES % R == 0: blocks are full and never straddle the boundary.
// R = 8 edges/block, 128 threads = 2 waves. em GEMM on bf16 MFMA (16x16x32),
// A-tile 16 rows (8 used), wave w computes cols 64w..64w+63 (heads 4w..4w+3).
template <int R>
__global__ __launch_bounds__(128, 4) void att_logit_kernel(
    const float* __restrict__ edge_attr,
    const float* __restrict__ eWT, /* [128][32] */
    const float* __restrict__ eb,
    const float* __restrict__ eg, const float* __restrict__ ebe,
    const float* __restrict__ loop_attr,
    const __bf16* __restrict__ cWeB_l, /* packed B-frag layout, 16384 bf16 */
    const float* __restrict__ catt_l,  /* [128] */
    const float* __restrict__ xl, const float* __restrict__ xr,
    const int* __restrict__ ei_src, const int* __restrict__ ei_dst,
    float* __restrict__ logit, float* __restrict__ mx) {
    __shared__ __align__(16) __bf16 ats[16 * ATS_LD];
    __shared__ __align__(16) float sattr[R * EDGE_IN];
    __shared__ float wred[2][R], wred2[2][R];
    __shared__ int ssrc[R], sdst[R];
    int j = threadIdx.x;
    int wave = j >> 6, lane = j & 63;
    long e0 = (long)blockIdx.x * R;
    bool real_block = (e0 < N_EDGES);
    if (real_block && j < R * 8) {
        ((float4*)sattr)[j] = ((const float4*)edge_attr)[e0 * 8 + j];
    }
    if (j < R) {
        long e = e0 + j;
        if (e < N_EDGES) { ssrc[j] = ei_src[e]; sdst[j] = ei_dst[e]; }
        else             { ssrc[j] = sdst[j] = (int)(e - N_EDGES); }
    }
    __syncthreads();
    if (real_block) {
        // edge-encode: val = edge_attr @ eW + eb
        float val[R];
        float ebj = eb[j];
#pragma unroll
        for (int r = 0; r < R; ++r) val[r] = ebj;
        const float4* ewr = (const float4*)(eWT + (size_t)j * EDGE_IN);
#pragma unroll 1
        for (int q = 0; q < 8; ++q) {
            float4 wq = ewr[q];
#pragma unroll
            for (int r = 0; r < R; ++r) {
                float4 a = *(const float4*)&sattr[r * EDGE_IN + q * 4];
                val[r] += dot4(a, wq);
            }
        }
        // LN across the 128 columns
#pragma unroll
        for (int r = 0; r < R; ++r) {
            float s = wave_sum(val[r]);
            if (lane == 0) wred[wave][r] = s;
        }
        __syncthreads();
#pragma unroll
        for (int r = 0; r < R; ++r) {
            float mean = (wred[0][r] + wred[1][r]) * (1.0f / HID);
            float d = val[r] - mean;
            val[r] = d;
            float s = wave_sum(d * d);
            if (lane == 0) wred2[wave][r] = s;
        }
        __syncthreads();
        float egj = eg[j], ebej = ebe[j];
#pragma unroll
        for (int r = 0; r < R; ++r) {
            float var = (wred2[0][r] + wred2[1][r]) * (1.0f / HID);
            ats[r * ATS_LD + j] = (__bf16)gelu_f(val[r] * rsqrtf(var + LN_EPS) * egj + ebej);
        }
    } else {
        // self-loop rows: loop_attr is already the final ea row
#pragma unroll
        for (int r = 0; r < R; ++r) {
            ats[r * ATS_LD + j] = (__bf16)loop_attr[(long)(e0 + r - N_EDGES) * HID + j];
        }
    }
    // rows 8..15 of ats stay garbage: they only feed D rows 8..15, which are discarded.
    __syncthreads();
    // MFMA em GEMM: D[16x64 per wave] = ats[16x128] @ cWe[128 x 64w..64w+63]
    int m_lane = lane & 15, quad = lane >> 4;
    f32x4_t acc[4];
#pragma unroll
    for (int t = 0; t < 4; ++t) acc[t] = (f32x4_t){0.0f, 0.0f, 0.0f, 0.0f};
    const bf16x8_t* bp = (const bf16x8_t*)cWeB_l;
#pragma unroll
    for (int step = 0; step < 4; ++step) {
        bf16x8_t afrag = *(const bf16x8_t*)&ats[m_lane * ATS_LD + step * 32 + quad * 8];
        int g = step * 4 + quad;
#pragma unroll
        for (int t = 0; t < 4; ++t) {
            int n = wave * 64 + t * 16 + m_lane;
            bf16x8_t bfrag = bp[g * 128 + n];
            acc[t] = __builtin_amdgcn_mfma_f32_16x16x32_bf16(afrag, bfrag, acc[t], 0, 0, 0);
        }
    }
    // epilogue: C layout col=lane&15, row=quad*4+reg; rows >= 8 are garbage (skip).
#pragma unroll
    for (int t = 0; t < 4; ++t) {
        int c = wave * 64 + t * 16 + m_lane;
        int h = wave * 4 + t;
        float cj = catt_l[c];
#pragma unroll
        for (int reg = 0; reg < 4; ++reg) {
            int r = quad * 4 + reg;
            if (r < R) {  // quad 0,1 only; uniform per 16-lane group
                int s = ssrc[r], d = sdst[r];
                float mval = xl[(long)s * HID + c] + xr[(long)d * HID + c] + acc[t][reg];
                mval = (mval > 0.0f) ? mval : 0.2f * mval;
                float p = mval * cj;
                p += __shfl_xor(p, 1);
                p += __shfl_xor(p, 2);
                p += __shfl_xor(p, 4);
                p += __shfl_xor(p, 8);
                if (m_lane == 0) {
                    logit[(e0 + r) * HEADS + h] = p;
                    atomicMaxF(&mx[(long)d * HEADS + h], p);
                }
            }
        }
    }
}

// ---------- exp(logit-mx), accumulate denominator ----------
__global__ void softmax_norm_kernel(const int* __restrict__ ei_dst, const float* __restrict__ mx,
                                    float* __restrict__ logit, float* __restrict__ den) {
    long idx = (long)blockIdx.x * blockDim.x + threadIdx.x;
    if (idx >= (long)EF * HEADS) return;
    long e = idx >> 3;
    int hh = (int)(idx & 7);
    int d = (e < N_EDGES) ? ei_dst[e] : (int)(e - N_EDGES);
    float ex = expf(logit[idx] - mx[(long)d * HEADS + hh]);
    logit[idx] = ex;
    atomicAdd(&den[(long)d * HEADS + hh], ex);
}

// ---------- alpha-weighted aggregation (float4: 4 cols/thread) ----------
__global__ void aggregate_kernel(const float* __restrict__ logit, const float* __restrict__ den,
                                 const float* __restrict__ xl,
                                 const int* __restrict__ ei_src, const int* __restrict__ ei_dst,
                                 float* __restrict__ aggout) {
    long idx = (long)blockIdx.x * blockDim.x + threadIdx.x;
    if (idx >= (long)EF * 32) return;
    long e = idx >> 5;
    int q = (int)(idx & 31);  // 4-col group
    int j0 = q << 2;
    int head = q >> 2;
    int s, d;
    if (e < N_EDGES) { s = ei_src[e]; d = ei_dst[e]; }
    else             { s = d = (int)(e - N_EDGES); }
    float alpha = logit[e * HEADS + head] / (den[(long)d * HEADS + head] + 1e-16f);
    float4 xv = *(const float4*)&xl[(long)s * HID + j0];
    float* dst = &aggout[(long)d * HID + j0];
    atomicAdd(dst + 0, alpha * xv.x);
    atomicAdd(dst + 1, alpha * xv.y);
    atomicAdd(dst + 2, alpha * xv.z);
    atomicAdd(dst + 3, alpha * xv.w);
}

// ---------- h = gelu(aggout + cbias) + h ----------
__global__ void residual_kernel(const float* __restrict__ aggout, const float* __restrict__ cbias_l,
                                float* __restrict__ h) {
    int idx = blockIdx.x * blockDim.x + threadIdx.x;
    if (idx >= N_NODES * HID) return;
    int j = idx & 127;
    h[idx] = gelu_f(aggout[idx] + cbias_l[j]) + h[idx];
}

// ---------- pooling ----------
#define POOL_NODES 64
__global__ __launch_bounds__(128) void pool_kernel(
    const float* __restrict__ h, const int* __restrict__ batch,
    float* __restrict__ gsum, float* __restrict__ gcnt) {
    __shared__ float acc[N_GRAPHS][HID];
    __shared__ float cnt_sh[N_GRAPHS];
    int j = threadIdx.x;
    for (int g = 0; g < N_GRAPHS; ++g) acc[g][j] = 0.0f;
    if (j < N_GRAPHS) cnt_sh[j] = 0.0f;
    __syncthreads();
    int n0 = blockIdx.x * POOL_NODES;
    for (int i = 0; i < POOL_NODES; ++i) {
        int n = n0 + i;
        if (n >= N_NODES) break;
        int g = batch[n];
        acc[g][j] += h[(long)n * HID + j];
        if (j == 0) cnt_sh[g] += 1.0f;
    }
    __syncthreads();
    for (int g = 0; g < N_GRAPHS; ++g) atomicAdd(&gsum[g * HID + j], acc[g][j]);
    if (j < N_GRAPHS) atomicAdd(&gcnt[j], cnt_sh[j]);
}

// ---------- props head ----------
__global__ __launch_bounds__(128) void props_kernel(
    const float* __restrict__ gsum, const float* __restrict__ gcnt,
    const float* __restrict__ pW1, const float* __restrict__ pb1,
    const float* __restrict__ pg, const float* __restrict__ pbe,
    const float* __restrict__ pW2, const float* __restrict__ pb2,
    float* __restrict__ out_props) {
    int g = blockIdx.x, j = threadIdx.x;
    __shared__ float feat[HID], red[HID], t2[HID];
    float c = fmaxf(gcnt[g], 1.0f);
    feat[j] = gsum[g * HID + j] / c;
    __syncthreads();
    float acc = pb1[j];
    for (int k = 0; k < HID; ++k) acc += feat[k] * pW1[k * HID + j];
    red[j] = acc;
    __syncthreads();
    for (int s = 64; s > 0; s >>= 1) { if (j < s) red[j] += red[j + s]; __syncthreads(); }
    float mean = red[0] * (1.0f / HID);
    __syncthreads();
    float dd = acc - mean;
    red[j] = dd * dd;
    __syncthreads();
    for (int s = 64; s > 0; s >>= 1) { if (j < s) red[j] += red[j + s]; __syncthreads(); }
    float var = red[0] * (1.0f / HID);
    t2[j] = gelu_f(dd * rsqrtf(var + LN_EPS) * pg[j] + pbe[j]);
    __syncthreads();
    if (j < COND) {
        float a = pb2[j];
        for (int k = 0; k < HID; ++k) a += t2[k] * pW2[k * COND + j];
        out_props[g * COND + j] = a;
    }
}

extern "C" void kernel_launch(void* const* d_in, const int* in_sizes, int n_in,
                              void* d_out, int out_size, void* d_ws, size_t ws_size,
                              hipStream_t stream) {
    const float* x        = (const float*)d_in[0];
    const float* edge_attr= (const float*)d_in[1];
    const float* t        = (const float*)d_in[2];
    const float* conds    = (const float*)d_in[3];
    const float* tW1      = (const float*)d_in[4];
    const float* tb1      = (const float*)d_in[5];
    const float* tW2      = (const float*)d_in[6];
    const float* tb2      = (const float*)d_in[7];
    const float* encW     = (const float*)d_in[8];
    const float* encb     = (const float*)d_in[9];
    const float* encg     = (const float*)d_in[10];
    const float* encbe    = (const float*)d_in[11];
    const float* eW       = (const float*)d_in[12];
    const float* eb       = (const float*)d_in[13];
    const float* eg       = (const float*)d_in[14];
    const float* ebe      = (const float*)d_in[15];
    const float* cWl      = (const float*)d_in[16];
    const float* cbl      = (const float*)d_in[17];
    const float* cWr      = (const float*)d_in[18];
    const float* cbr      = (const float*)d_in[19];
    const float* cWe      = (const float*)d_in[20];
    const float* catt     = (const float*)d_in[21];
    const float* cbias    = (const float*)d_in[22];
    const float* nW1      = (const float*)d_in[23];
    const float* nb1      = (const float*)d_in[24];
    const float* ng       = (const float*)d_in[25];
    const float* nbe      = (const float*)d_in[26];
    const float* nW2      = (const float*)d_in[27];
    const float* nb2      = (const float*)d_in[28];
    const float* pW1      = (const float*)d_in[29];
    const float* pb1      = (const float*)d_in[30];
    const float* pg       = (const float*)d_in[31];
    const float* pbe      = (const float*)d_in[32];
    const float* pW2      = (const float*)d_in[33];
    const float* pb2      = (const float*)d_in[34];
    const int* edge_index = (const int*)d_in[35];
    const int* batch      = (const int*)d_in[36];
    const int* ei_src = edge_index;
    const int* ei_dst = edge_index + N_EDGES;

    // workspace layout (~95 MB of f32)
    float* ws = (float*)d_ws;
    size_t off = 0;
    auto alloc = [&](size_t n) { float* p = ws + off; off += n; return p; };
    float* t_emb     = alloc((size_t)N_GRAPHS * HID);
    float* h         = alloc((size_t)N_NODES * HID);
    float* loop_attr = alloc((size_t)N_NODES * HID);
    float* cnt       = alloc((size_t)N_NODES);
    float* xl        = alloc((size_t)N_NODES * HID);
    float* xr        = alloc((size_t)N_NODES * HID);
    float* logit     = alloc((size_t)EF * HEADS);      // 4.08M floats
    float* mx        = alloc((size_t)N_NODES * HEADS);
    float* den       = alloc((size_t)N_NODES * HEADS);
    float* aggout    = alloc((size_t)N_NODES * HID);
    float* gsum      = alloc((size_t)N_GRAPHS * HID);
    float* gcnt      = alloc((size_t)N_GRAPHS);
    float* wT12      = alloc((size_t)12 * 16384);      // cWlT[4] | cWrT[4] | cWeT[4]
    float* eWT       = alloc((size_t)HID * EDGE_IN);
    float* nW1T      = alloc((size_t)HID * HID);
    float* nW2T      = alloc((size_t)NODE_OUT * HID);
    __bf16* cWeB     = (__bf16*)alloc((size_t)4 * 16384 / 2); // 4 layers, bf16-packed
    // aliases (disjoint lifetimes):
    float* xc   = logit;  // [N,72] pre-layer only; logit is bigger
    float* tmp1 = xl;     // post-layer only
    (void)ws_size; (void)in_sizes; (void)n_in; (void)out_size;

    float* pred_noise = (float*)d_out;                              // [N,64]
    float* pred_props = (float*)d_out + (size_t)N_NODES * NODE_OUT; // [16,8]

    // 0. weight transposes + bf16 pack
    hipLaunchKernelGGL(batched_transpose12_kernel, dim3((12 * 16384 + 255) / 256), dim3(256), 0,
                       stream, cWl, cWr, cWe, wT12);
    hipLaunchKernelGGL(transpose_kernel, dim3((EDGE_IN * HID + 255) / 256), dim3(256), 0, stream,
                       eW, eWT, EDGE_IN, HID);
    hipLaunchKernelGGL(transpose_kernel, dim3((HID * HID + 255) / 256), dim3(256), 0, stream,
                       nW1, nW1T, HID, HID);
    hipLaunchKernelGGL(transpose_kernel, dim3((HID * NODE_OUT + 255) / 256), dim3(256), 0, stream,
                       nW2, nW2T, HID, NODE_OUT);
    hipLaunchKernelGGL(pack_cwe_bf16_kernel, dim3((4 * 16384 + 255) / 256), dim3(256), 0, stream,
                       cWe, cWeB);

    // 1. time MLP
    hipLaunchKernelGGL(time_mlp_kernel, dim3(N_GRAPHS), dim3(HID), 0, stream,
                       t, tW1, tb1, tW2, tb2, t_emb);
    // 2. concat
    hipLaunchKernelGGL(concat_kernel, dim3((N_NODES * 72 + 255) / 256), dim3(256), 0, stream,
                       x, conds, batch, xc);
    // 3. node encoder gemm + LN/GELU (+t_emb[batch])
    hipLaunchKernelGGL((gemm_kernel<HID, 8>), dim3(N_NODES / 8), dim3(HID), 0, stream,
                       xc, encW, encb, h, N_NODES, 72);
    hipLaunchKernelGGL(ln_gelu_kernel, dim3(N_NODES), dim3(HID), 0, stream,
                       h, encg, encbe, t_emb, batch);
    // 4. self-loop attr = segment-mean of encoded edge_attr over dst (encode fused)
    hipLaunchKernelGGL(zero_kernel, dim3(1024), dim3(256), 0, stream,
                       loop_attr, (long)N_NODES * HID);
    hipLaunchKernelGGL(zero_kernel, dim3(64), dim3(256), 0, stream, cnt, (long)N_NODES);
    hipLaunchKernelGGL((edge_enc_loop_kernel<8>), dim3(N_EDGES / 8), dim3(HID), 0, stream,
                       edge_attr, eWT, eb, eg, ebe, ei_dst, loop_attr, cnt);
    hipLaunchKernelGGL(loop_div_kernel, dim3((N_NODES * HID + 255) / 256), dim3(256), 0, stream,
                       loop_attr, cnt);

    // 5. layers
    for (int l = 0; l < NLAYERS; ++l) {
        const float* cWlT_l = wT12 + (size_t)l * 16384;
        const float* cWrT_l = wT12 + (size_t)(4 + l) * 16384;
        const __bf16* cWeB_l = cWeB + (size_t)l * 16384;
        const float* cbl_l = cbl + (size_t)l * HID;
        const float* cbr_l = cbr + (size_t)l * HID;
        const float* catt_l = catt + (size_t)l * HID;
        const float* cbias_l = cbias + (size_t)l * HID;

        hipLaunchKernelGGL((gemm_t_kernel<HID, 8>), dim3(N_NODES / 8), dim3(HID), 0, stream,
                           h, cWlT_l, cbl_l, xl, N_NODES);
        hipLaunchKernelGGL((gemm_t_kernel<HID, 8>), dim3(N_NODES / 8), dim3(HID), 0, stream,
                           h, cWrT_l, cbr_l, xr, N_NODES);
        hipLaunchKernelGGL(init_mx_den_kernel, dim3((N_NODES * HEADS + 255) / 256), dim3(256), 0,
                           stream, mx, den);
        hipLaunchKernelGGL((att_logit_kernel<8>), dim3(EF / 8), dim3(HID), 0, stream,
                           edge_attr, eWT, eb, eg, ebe, loop_attr,
                           cWeB_l, catt_l, xl, xr, ei_src, ei_dst, logit, mx);
        hipLaunchKernelGGL(softmax_norm_kernel,
                           dim3((int)(((long)EF * HEADS + 255) / 256)), dim3(256), 0, stream,
                           ei_dst, mx, logit, den);
        hipLaunchKernelGGL(zero_kernel, dim3(1024), dim3(256), 0, stream,
                           aggout, (long)N_NODES * HID);
        hipLaunchKernelGGL(aggregate_kernel,
                           dim3((int)(((long)EF * 32 + 255) / 256)), dim3(256), 0, stream,
                           logit, den, xl, ei_src, ei_dst, aggout);
        hipLaunchKernelGGL(residual_kernel, dim3((N_NODES * HID + 255) / 256), dim3(256), 0, stream,
                           aggout, cbias_l, h);
    }

    // 6. noise head
    hipLaunchKernelGGL((gemm_t_kernel<HID, 8>), dim3(N_NODES / 8), dim3(HID), 0, stream,
                       h, nW1T, nb1, tmp1, N_NODES);
    hipLaunchKernelGGL(ln_gelu_kernel, dim3(N_NODES), dim3(HID), 0, stream,
                       tmp1, ng, nbe, (const float*)nullptr, (const int*)nullptr);
    hipLaunchKernelGGL((gemm_t_kernel<NODE_OUT, 8>), dim3(N_NODES / 8), dim3(NODE_OUT), 0, stream,
                       tmp1, nW2T, nb2, pred_noise, N_NODES);

    // 7. pooling + props head
    hipLaunchKernelGGL(zero_kernel, dim3(4), dim3(256), 0, stream,
                       gsum, (long)N_GRAPHS * HID);
    hipLaunchKernelGGL(zero_kernel, dim3(1), dim3(64), 0, stream, gcnt, (long)N_GRAPHS);
    hipLaunchKernelGGL(pool_kernel, dim3((N_NODES + POOL_NODES - 1) / POOL_NODES), dim3(HID), 0,
                       stream, h, batch, gsum, gcnt);
    hipLaunchKernelGGL(props_kernel, dim3(N_GRAPHS), dim3(HID), 0, stream,
                       gsum, gcnt, pW1, pb1, pg, pbe, pW2, pb2, pred_props);
}